// Round 11
// baseline (25400.874 us; speedup 1.0000x reference)
//
#include <hip/hip_runtime.h>
#include <hip/hip_bf16.h>

// ---------------------------------------------------------------------------
// AutoregressiveBeamDecoder: B=256, T=128, D=512, H=1024, NB=64, HH=8
// Round 11: ONE persistent kernel; 8 independent row-groups (32 rows each),
// group = bid&7 (XCD round-robin heuristic). Group-local flag barriers
// (no RMW contention; agent fences for safety). Phases per step:
//  P1 gates: 24 gate blocks (32x256, K=1024) + 4 cin + 4 octx (K=512)
//  P2 gru:   1 row/block (no redundancy), LN stats -> mbuf/isbuf
//  P3 o-GEMM: K-split 4 into g6 slots 0..3 (free after P2)
//  P4 logits + argmax + x build: 1 row/block
// GEMM core: A-hi/lo + B-hi staged in LDS (51KB); B-lo read as packed
// fragments direct from global (round-6 verified layout, lo only).
// C = Ahi@Bhi + Ahi@Blo + Alo@Bhi (3x mfma_f32_16x16x32_bf16, fp32 accum)
// ---------------------------------------------------------------------------

#define TS 68
#define LDPA 40
constexpr int SZ = 262144;     // 256*1024
constexpr int TT = 128;
constexpr int LDA_CTX = 65536; // T*D

typedef __attribute__((ext_vector_type(8))) short short8_t;
typedef __attribute__((ext_vector_type(4))) float f32x4;

// ---------------- bf16 split helpers ---------------------------------------

__device__ __forceinline__ unsigned short f2bf_rne(float v) {
    unsigned u = __float_as_uint(v);
    unsigned r = u + 0x7fffu + ((u >> 16) & 1u);
    return (unsigned short)(r >> 16);
}
__device__ __forceinline__ float bfbits2f(unsigned short h) {
    return __uint_as_float(((unsigned)h) << 16);
}
__device__ __forceinline__ void split2(float v, unsigned short& h, unsigned short& l) {
    h = f2bf_rne(v);
    l = f2bf_rne(v - bfbits2f(h));
}
__device__ __forceinline__ void splitA8(const float4& v0, const float4& v1,
                                        short8_t& hi, short8_t& lo) {
    unsigned short h[8], l[8];
    split2(v0.x, h[0], l[0]); split2(v0.y, h[1], l[1]);
    split2(v0.z, h[2], l[2]); split2(v0.w, h[3], l[3]);
    split2(v1.x, h[4], l[4]); split2(v1.y, h[5], l[5]);
    split2(v1.z, h[6], l[6]); split2(v1.w, h[7], l[7]);
    hi = short8_t{(short)h[0],(short)h[1],(short)h[2],(short)h[3],
                  (short)h[4],(short)h[5],(short)h[6],(short)h[7]};
    lo = short8_t{(short)l[0],(short)l[1],(short)l[2],(short)l[3],
                  (short)l[4],(short)l[5],(short)l[6],(short)l[7]};
}

// ---------------- group barrier (flag array, no RMW) ------------------------

#define GBAR(ph) gbar(flags, gen, grp, rank, (unsigned)(t * 4 + (ph)))

__device__ __forceinline__ void gbar(unsigned* flags, unsigned* gen,
                                     int g, int rank, unsigned c)
{
    __syncthreads();
    if (threadIdx.x == 0) {
        __threadfence();   // release group data (agent scope)
        __hip_atomic_store(&flags[(g * 32 + rank) * 16], c,
                           __ATOMIC_RELEASE, __HIP_MEMORY_SCOPE_AGENT);
        if (rank == 0) {
            for (int r = 1; r < 32; ++r) {
                while (__hip_atomic_load(&flags[(g * 32 + r) * 16],
                                         __ATOMIC_RELAXED, __HIP_MEMORY_SCOPE_AGENT) < c)
                    __builtin_amdgcn_s_sleep(2);
            }
            __threadfence();
            __hip_atomic_store(&gen[g * 16], c, __ATOMIC_RELEASE,
                               __HIP_MEMORY_SCOPE_AGENT);
        } else {
            while (__hip_atomic_load(&gen[g * 16], __ATOMIC_RELAXED,
                                     __HIP_MEMORY_SCOPE_AGENT) < c)
                __builtin_amdgcn_s_sleep(2);
            __threadfence();   // acquire
        }
    }
    __syncthreads();
}

// ---------------- core: tile 32(M) x 256(N), BK=32 --------------------------
// 256 thr = 4 waves; wave wid covers cols wid*64 (acc[2][4], m-frags rows l15,
// l15+16). A-hi/lo + B-hi in LDS; B-lo packed-frag direct from global.
// LDS shorts: Ah[32*40]=1280 | Al 1280 | Bh[256*40]=10240  -> 12800/buf, x2.

constexpr int AOF11 = 1280;
constexpr int BOF11 = 2560;
constexpr int BUF11 = 12800;

__device__ __forceinline__ void wout11(float* C, int b0, int n0,
                                       const float* bias, f32x4 acc[2][4],
                                       int lane, int wid)
{
    const int l15 = lane & 15, g4 = (lane >> 4) * 4;
#pragma unroll
    for (int mi = 0; mi < 2; ++mi) {
#pragma unroll
        for (int ni = 0; ni < 4; ++ni) {
            int col = n0 + wid * 64 + ni * 16 + l15;
            float bv = bias ? bias[col] : 0.f;
#pragma unroll
            for (int r = 0; r < 4; ++r) {
                int row = b0 + mi * 16 + g4 + r;
                C[(size_t)row * 1024 + col] = acc[mi][ni][r] + bv;
            }
        }
    }
}

// A pre-split bf16 variant
__device__ __forceinline__ void core11b(
    const unsigned short* __restrict__ Ah, const unsigned short* __restrict__ Al,
    int lda, int b0,
    const unsigned short* __restrict__ Bh, int ldb,      // Bh already + nmat row base
    const unsigned short* __restrict__ BlP, int nKs, int ksbase, int nfb,
    int nIter, unsigned short* sm, f32x4 acc[2][4])
{
    const int tid = threadIdx.x, lane = tid & 63, wid = tid >> 6;
    const int l15 = lane & 15, kg = (lane >> 4) * 8;
    const int arow = tid >> 2, acol = (tid & 3) * 8;     // tid<128
    const bool doA = tid < 128;

    const unsigned short* gAh = Ah + (size_t)(b0 + arow) * lda + ksbase * 32 + acol;
    const unsigned short* gAl = Al + (size_t)(b0 + arow) * lda + ksbase * 32 + acol;
    const unsigned short* gBh = Bh + (size_t)tid * ldb + ksbase * 32;
    const unsigned short* pBl[4];
#pragma unroll
    for (int ni = 0; ni < 4; ++ni)
        pBl[ni] = BlP + ((size_t)(nfb + ni) * nKs + ksbase) * 512 + lane * 8;

    short8_t cBl[4], nBl[4];
    {
        if (doA) {
            short8_t a_h = *(const short8_t*)gAh;
            short8_t a_l = *(const short8_t*)gAl;
            *(short8_t*)&sm[arow * LDPA + acol] = a_h;
            *(short8_t*)&sm[AOF11 + arow * LDPA + acol] = a_l;
        }
#pragma unroll
        for (int q = 0; q < 4; ++q) {
            short8_t b = *(const short8_t*)(gBh + q * 8);
            *(short8_t*)&sm[BOF11 + tid * LDPA + q * 8] = b;
        }
#pragma unroll
        for (int ni = 0; ni < 4; ++ni) cBl[ni] = *(const short8_t*)(pBl[ni]);
    }
    __syncthreads();

    int cur = 0;
    for (int i = 0; i < nIter; ++i) {
        short8_t a_h, a_l, bq[4];
        if (i + 1 < nIter) {
            const int ko = (i + 1) * 32;
            if (doA) {
                a_h = *(const short8_t*)(gAh + ko);
                a_l = *(const short8_t*)(gAl + ko);
            }
#pragma unroll
            for (int q = 0; q < 4; ++q)
                bq[q] = *(const short8_t*)(gBh + ko + q * 8);
#pragma unroll
            for (int ni = 0; ni < 4; ++ni)
                nBl[ni] = *(const short8_t*)(pBl[ni] + (size_t)(i + 1) * 512);
        }
        const unsigned short* S = sm + cur * BUF11;
        short8_t afh[2], afl[2];
#pragma unroll
        for (int mi = 0; mi < 2; ++mi) {
            afh[mi] = *(const short8_t*)&S[(mi * 16 + l15) * LDPA + kg];
            afl[mi] = *(const short8_t*)&S[AOF11 + (mi * 16 + l15) * LDPA + kg];
        }
#pragma unroll
        for (int ni = 0; ni < 4; ++ni) {
            short8_t b_h = *(const short8_t*)&S[BOF11 + (wid * 64 + ni * 16 + l15) * LDPA + kg];
#pragma unroll
            for (int mi = 0; mi < 2; ++mi) {
                acc[mi][ni] = __builtin_amdgcn_mfma_f32_16x16x32_bf16(afh[mi], b_h, acc[mi][ni], 0, 0, 0);
                acc[mi][ni] = __builtin_amdgcn_mfma_f32_16x16x32_bf16(afh[mi], cBl[ni], acc[mi][ni], 0, 0, 0);
                acc[mi][ni] = __builtin_amdgcn_mfma_f32_16x16x32_bf16(afl[mi], b_h, acc[mi][ni], 0, 0, 0);
            }
        }
        if (i + 1 < nIter) {
            unsigned short* N_ = sm + (cur ^ 1) * BUF11;
            if (doA) {
                *(short8_t*)&N_[arow * LDPA + acol] = a_h;
                *(short8_t*)&N_[AOF11 + arow * LDPA + acol] = a_l;
            }
#pragma unroll
            for (int q = 0; q < 4; ++q)
                *(short8_t*)&N_[BOF11 + tid * LDPA + q * 8] = bq[q];
        }
        __syncthreads();
        cur ^= 1;
#pragma unroll
        for (int ni = 0; ni < 4; ++ni) cBl[ni] = nBl[ni];
    }
}

// A fp32 variant (ctx blocks; in-register split on 32x32 stage)
__device__ __forceinline__ void core11f(
    const float* __restrict__ Af, int lda, int b0,
    const unsigned short* __restrict__ Bh, int ldb,
    const unsigned short* __restrict__ BlP, int nKs, int ksbase, int nfb,
    int nIter, unsigned short* sm, f32x4 acc[2][4])
{
    const int tid = threadIdx.x, lane = tid & 63, wid = tid >> 6;
    const int l15 = lane & 15, kg = (lane >> 4) * 8;
    const int arow = tid >> 2, acol = (tid & 3) * 8;
    const bool doA = tid < 128;

    const float* gA = Af + (size_t)(b0 + arow) * lda + ksbase * 32 + acol;
    const unsigned short* gBh = Bh + (size_t)tid * ldb + ksbase * 32;
    const unsigned short* pBl[4];
#pragma unroll
    for (int ni = 0; ni < 4; ++ni)
        pBl[ni] = BlP + ((size_t)(nfb + ni) * nKs + ksbase) * 512 + lane * 8;

    short8_t cBl[4], nBl[4];
    {
        if (doA) {
            float4 a0 = *(const float4*)gA;
            float4 a1 = *(const float4*)(gA + 4);
            short8_t ah, al;
            splitA8(a0, a1, ah, al);
            *(short8_t*)&sm[arow * LDPA + acol] = ah;
            *(short8_t*)&sm[AOF11 + arow * LDPA + acol] = al;
        }
#pragma unroll
        for (int q = 0; q < 4; ++q) {
            short8_t b = *(const short8_t*)(gBh + q * 8);
            *(short8_t*)&sm[BOF11 + tid * LDPA + q * 8] = b;
        }
#pragma unroll
        for (int ni = 0; ni < 4; ++ni) cBl[ni] = *(const short8_t*)(pBl[ni]);
    }
    __syncthreads();

    int cur = 0;
    for (int i = 0; i < nIter; ++i) {
        float4 a0, a1;
        short8_t bq[4];
        if (i + 1 < nIter) {
            const int ko = (i + 1) * 32;
            if (doA) {
                a0 = *(const float4*)(gA + ko);
                a1 = *(const float4*)(gA + ko + 4);
            }
#pragma unroll
            for (int q = 0; q < 4; ++q)
                bq[q] = *(const short8_t*)(gBh + ko + q * 8);
#pragma unroll
            for (int ni = 0; ni < 4; ++ni)
                nBl[ni] = *(const short8_t*)(pBl[ni] + (size_t)(i + 1) * 512);
        }
        const unsigned short* S = sm + cur * BUF11;
        short8_t afh[2], afl[2];
#pragma unroll
        for (int mi = 0; mi < 2; ++mi) {
            afh[mi] = *(const short8_t*)&S[(mi * 16 + l15) * LDPA + kg];
            afl[mi] = *(const short8_t*)&S[AOF11 + (mi * 16 + l15) * LDPA + kg];
        }
#pragma unroll
        for (int ni = 0; ni < 4; ++ni) {
            short8_t b_h = *(const short8_t*)&S[BOF11 + (wid * 64 + ni * 16 + l15) * LDPA + kg];
#pragma unroll
            for (int mi = 0; mi < 2; ++mi) {
                acc[mi][ni] = __builtin_amdgcn_mfma_f32_16x16x32_bf16(afh[mi], b_h, acc[mi][ni], 0, 0, 0);
                acc[mi][ni] = __builtin_amdgcn_mfma_f32_16x16x32_bf16(afh[mi], cBl[ni], acc[mi][ni], 0, 0, 0);
                acc[mi][ni] = __builtin_amdgcn_mfma_f32_16x16x32_bf16(afl[mi], b_h, acc[mi][ni], 0, 0, 0);
            }
        }
        if (i + 1 < nIter) {
            unsigned short* N_ = sm + (cur ^ 1) * BUF11;
            if (doA) {
                short8_t ah, al;
                splitA8(a0, a1, ah, al);
                *(short8_t*)&N_[arow * LDPA + acol] = ah;
                *(short8_t*)&N_[AOF11 + arow * LDPA + acol] = al;
            }
#pragma unroll
            for (int q = 0; q < 4; ++q)
                *(short8_t*)&N_[BOF11 + tid * LDPA + q * 8] = bq[q];
        }
        __syncthreads();
        cur ^= 1;
#pragma unroll
        for (int ni = 0; ni < 4; ++ni) cBl[ni] = nBl[ni];
    }
}

// ---------------- persistent kernel ----------------------------------------

__global__ __launch_bounds__(256) void persist11_kernel(
    unsigned short* __restrict__ xh, unsigned short* __restrict__ xl,
    unsigned short* __restrict__ hh, unsigned short* __restrict__ hl,
    float* __restrict__ hbuf, const float* __restrict__ ctx,
    const unsigned short* __restrict__ wih_hi, const unsigned short* __restrict__ wih_loP,
    const unsigned short* __restrict__ whh_hi, const unsigned short* __restrict__ whh_loP,
    const unsigned short* __restrict__ wo1k_hi, const unsigned short* __restrict__ wo1k_loP,
    const unsigned short* __restrict__ wo1c_hi, const unsigned short* __restrict__ wo1c_loP,
    const unsigned short* __restrict__ wcin_hi, const unsigned short* __restrict__ wcin_loP,
    const float* __restrict__ b_in, const float* __restrict__ b_o1,
    const float* __restrict__ b_ih, const float* __restrict__ b_hh,
    float* __restrict__ g6, float* __restrict__ cin, float* __restrict__ octx,
    float* __restrict__ mbuf, float* __restrict__ isbuf,
    const float* __restrict__ Wo2t, const float* __restrict__ b_o2,
    const float* __restrict__ uv, const float* __restrict__ bpart,
    int* __restrict__ prev, float* __restrict__ out,
    unsigned* __restrict__ flags, unsigned* __restrict__ gen)
{
    __shared__ __align__(16) unsigned short sm[2 * BUF11];   // 51,200 B
    const int bid = blockIdx.x, tid = threadIdx.x;
    const int grp = bid & 7, rank = bid >> 3;
    const int b0 = grp * 32;
    const int lane = tid & 63, wid = tid >> 6;

    for (int t = 0; t < TT; ++t) {
        // ================= P1: gates + cin(t+1) + octx(t) ==================
        if (rank < 24) {
            const int z = rank >> 2, zg = (z < 3) ? z : z - 3;
            const int n0 = (rank & 3) * 256;
            const unsigned short* Ah = (z < 3) ? xh : hh;
            const unsigned short* Al = (z < 3) ? xl : hl;
            const unsigned short* Bh = ((z < 3) ? wih_hi : whh_hi)
                                       + (size_t)(zg * 1024 + n0) * 1024;
            const unsigned short* BlP = (z < 3) ? wih_loP : whh_loP;
            const int nfb = ((zg * 1024 + n0) >> 4) + wid * 4;
            f32x4 acc[2][4] = {};
            core11b(Ah, Al, 1024, b0, Bh, 1024, BlP, 32, 0, nfb, 32, sm, acc);
            wout11(g6 + (size_t)z * SZ, b0, n0, nullptr, acc, lane, wid);
        } else if (rank < 28) {
            if (t + 1 < TT) {
                const int n0 = (rank - 24) * 256;
                f32x4 acc[2][4] = {};
                core11f(ctx + (size_t)(t + 1) * 512, LDA_CTX, b0,
                        wcin_hi + (size_t)n0 * 512, 512,
                        wcin_loP, 16, 0, (n0 >> 4) + wid * 4, 16, sm, acc);
                wout11(cin, b0, n0, b_in, acc, lane, wid);
            }
        } else {
            const int n0 = (rank - 28) * 256;
            f32x4 acc[2][4] = {};
            core11f(ctx + (size_t)t * 512, LDA_CTX, b0,
                    wo1c_hi + (size_t)n0 * 512, 512,
                    wo1c_loP, 16, 0, (n0 >> 4) + wid * 4, 16, sm, acc);
            wout11(octx, b0, n0, b_o1, acc, lane, wid);
        }
        GBAR(1);

        // ================= P2: gru + LN stats (1 row/block) ================
        {
            float* ls = (float*)sm;
            float* lq = ls + 8;
            const int row = b0 + rank;
            const int j = tid * 4;
            size_t base = (size_t)row * 1024 + j;
            float4 xr = *(const float4*)(g6 + base);
            float4 xz = *(const float4*)(g6 + (size_t)SZ + base);
            float4 xn = *(const float4*)(g6 + 2 * (size_t)SZ + base);
            float4 hr = *(const float4*)(g6 + 3 * (size_t)SZ + base);
            float4 hz = *(const float4*)(g6 + 4 * (size_t)SZ + base);
            float4 hn = *(const float4*)(g6 + 5 * (size_t)SZ + base);
            float4 ho = *(const float4*)(hbuf + base);
            float4 bi0 = *(const float4*)(b_ih + j);
            float4 bi1 = *(const float4*)(b_ih + 1024 + j);
            float4 bi2 = *(const float4*)(b_ih + 2048 + j);
            float4 bh0 = *(const float4*)(b_hh + j);
            float4 bh1 = *(const float4*)(b_hh + 1024 + j);
            float4 bh2 = *(const float4*)(b_hh + 2048 + j);
            float4 hv;
            {
                float rr = 1.f / (1.f + expf(-((xr.x + bi0.x) + (hr.x + bh0.x))));
                float zz = 1.f / (1.f + expf(-((xz.x + bi1.x) + (hz.x + bh1.x))));
                float nn = tanhf((xn.x + bi2.x) + rr * (hn.x + bh2.x));
                hv.x = (1.f - zz) * nn + zz * ho.x;
            }
            {
                float rr = 1.f / (1.f + expf(-((xr.y + bi0.y) + (hr.y + bh0.y))));
                float zz = 1.f / (1.f + expf(-((xz.y + bi1.y) + (hz.y + bh1.y))));
                float nn = tanhf((xn.y + bi2.y) + rr * (hn.y + bh2.y));
                hv.y = (1.f - zz) * nn + zz * ho.y;
            }
            {
                float rr = 1.f / (1.f + expf(-((xr.z + bi0.z) + (hr.z + bh0.z))));
                float zz = 1.f / (1.f + expf(-((xz.z + bi1.z) + (hz.z + bh1.z))));
                float nn = tanhf((xn.z + bi2.z) + rr * (hn.z + bh2.z));
                hv.z = (1.f - zz) * nn + zz * ho.z;
            }
            {
                float rr = 1.f / (1.f + expf(-((xr.w + bi0.w) + (hr.w + bh0.w))));
                float zz = 1.f / (1.f + expf(-((xz.w + bi1.w) + (hz.w + bh1.w))));
                float nn = tanhf((xn.w + bi2.w) + rr * (hn.w + bh2.w));
                hv.w = (1.f - zz) * nn + zz * ho.w;
            }
            *(float4*)(hbuf + base) = hv;
            ushort4 h4, l4;
            split2(hv.x, h4.x, l4.x); split2(hv.y, h4.y, l4.y);
            split2(hv.z, h4.z, l4.z); split2(hv.w, h4.w, l4.w);
            *(ushort4*)(hh + base) = h4;
            *(ushort4*)(hl + base) = l4;
            float s = hv.x + hv.y + hv.z + hv.w;
            float q = hv.x * hv.x + hv.y * hv.y + hv.z * hv.z + hv.w * hv.w;
            for (int off = 32; off; off >>= 1) {
                s += __shfl_down(s, off);
                q += __shfl_down(q, off);
            }
            if (lane == 0) { ls[wid] = s; lq[wid] = q; }
            __syncthreads();
            if (tid == 0) {
                float S = ls[0] + ls[1] + ls[2] + ls[3];
                float Q = lq[0] + lq[1] + lq[2] + lq[3];
                float m = S * (1.f / 1024.f);
                mbuf[row] = m;
                isbuf[row] = rsqrtf(Q * (1.f / 1024.f) - m * m + 1e-5f);
            }
        }
        GBAR(2);

        // ================= P3: o-GEMM K-split 4 -> g6[0..3] ================
        if (rank < 16) {
            const int n0 = (rank & 3) * 256;
            const int ks = rank >> 2;            // 0..3, K slice 256
            f32x4 acc[2][4] = {};
            core11b(hh, hl, 1024, b0,
                    wo1k_hi + (size_t)n0 * 1024, 1024,
                    wo1k_loP, 32, ks * 8, (n0 >> 4) + wid * 4, 8, sm, acc);
            wout11(g6 + (size_t)ks * SZ, b0, n0, nullptr, acc, lane, wid);
        }
        GBAR(3);

        // ============ P4: o assemble + logits + argmax + x build ===========
        {
            float* osf = (float*)sm;              // 1024 floats
            float* red = osf + 1024;              // 4*64
            int* sidxp = (int*)(red + 256);
            const int row = b0 + rank;
            const int j = tid * 4;
            size_t base = (size_t)row * 1024 + j;
            {
                float4 p0 = *(const float4*)(g6 + base);
                float4 p1 = *(const float4*)(g6 + (size_t)SZ + base);
                float4 p2 = *(const float4*)(g6 + 2 * (size_t)SZ + base);
                float4 p3 = *(const float4*)(g6 + 3 * (size_t)SZ + base);
                float4 oc = *(const float4*)(octx + base);
                float4 u4 = *(const float4*)(uv + j);
                float4 v4 = *(const float4*)(uv + 1024 + j);
                float m = mbuf[row], is = isbuf[row];
                float4 o4;
                o4.x = fmaxf((p0.x + p1.x + p2.x + p3.x - m * u4.x) * is + v4.x + oc.x, 0.f);
                o4.y = fmaxf((p0.y + p1.y + p2.y + p3.y - m * u4.y) * is + v4.y + oc.y, 0.f);
                o4.z = fmaxf((p0.z + p1.z + p2.z + p3.z - m * u4.z) * is + v4.z + oc.z, 0.f);
                o4.w = fmaxf((p0.w + p1.w + p2.w + p3.w - m * u4.w) * is + v4.w + oc.w, 0.f);
                *(float4*)&osf[j] = o4;
            }
            __syncthreads();
            {
                int n = tid & 63, seg = tid >> 6;
                float p = 0.f;
                int k0 = seg * 256;
                for (int k = k0; k < k0 + 256; ++k)
                    p += osf[k] * Wo2t[(size_t)k * 64 + n];
                red[seg * 64 + n] = p;
            }
            __syncthreads();
            if (tid < 64) {
                float lg = red[tid] + red[64 + tid] + red[128 + tid] + red[192 + tid] + b_o2[tid];
                out[(size_t)row * (TT * 64) + t * 64 + tid] = lg;
                float v = lg; int idx = tid;
                for (int off = 32; off; off >>= 1) {
                    float ov = __shfl_xor(v, off);
                    int oi = __shfl_xor(idx, off);
                    if (ov > v || (ov == v && oi < idx)) { v = ov; idx = oi; }
                }
                if (tid == 0) { prev[row] = idx; sidxp[0] = idx; }
            }
            __syncthreads();
            if (t + 1 < TT) {
                int pb = sidxp[0];
                float4 cv = *(const float4*)(cin + base);
                float4 bv = *(const float4*)(bpart + (size_t)pb * 1024 + j);
                float4 xv;
                xv.x = fmaxf(cv.x + bv.x, 0.f);
                xv.y = fmaxf(cv.y + bv.y, 0.f);
                xv.z = fmaxf(cv.z + bv.z, 0.f);
                xv.w = fmaxf(cv.w + bv.w, 0.f);
                ushort4 h4, l4;
                split2(xv.x, h4.x, l4.x); split2(xv.y, h4.y, l4.y);
                split2(xv.z, h4.z, l4.z); split2(xv.w, h4.w, l4.w);
                *(ushort4*)(xh + base) = h4;
                *(ushort4*)(xl + base) = l4;
            }
        }
        GBAR(4);
    }
}

// ---------------- fp32 tiled GEMM core (setup + fallback) ------------------

__device__ __forceinline__ void gemm_tile64(
    const float* __restrict__ A, int lda, int Mlim, int b0,
    const float* __restrict__ W, int ldw, int n0, int K,
    float* At, float* Wt, float acc[4][4])
{
    const int tid = threadIdx.x;
    const int tx = tid & 15, ty = tid >> 4;
    const int r = tid >> 2, c0 = (tid & 3) << 2;
    for (int k0 = 0; k0 < K; k0 += 16) {
        float4 av = make_float4(0.f, 0.f, 0.f, 0.f);
        if (b0 + r < Mlim)
            av = *(const float4*)(A + (size_t)(b0 + r) * lda + k0 + c0);
        float4 wv = *(const float4*)(W + (size_t)(n0 + r) * ldw + k0 + c0);
        __syncthreads();
        At[(c0+0)*TS + r] = av.x; At[(c0+1)*TS + r] = av.y;
        At[(c0+2)*TS + r] = av.z; At[(c0+3)*TS + r] = av.w;
        Wt[(c0+0)*TS + r] = wv.x; Wt[(c0+1)*TS + r] = wv.y;
        Wt[(c0+2)*TS + r] = wv.z; Wt[(c0+3)*TS + r] = wv.w;
        __syncthreads();
#pragma unroll
        for (int kk = 0; kk < 16; ++kk) {
            float4 a = *(const float4*)(At + kk*TS + ty*4);
            float4 w = *(const float4*)(Wt + kk*TS + tx*4);
            acc[0][0] += a.x*w.x; acc[0][1] += a.x*w.y; acc[0][2] += a.x*w.z; acc[0][3] += a.x*w.w;
            acc[1][0] += a.y*w.x; acc[1][1] += a.y*w.y; acc[1][2] += a.y*w.z; acc[1][3] += a.y*w.w;
            acc[2][0] += a.z*w.x; acc[2][1] += a.z*w.y; acc[2][2] += a.z*w.z; acc[2][3] += a.z*w.w;
            acc[3][0] += a.w*w.x; acc[3][1] += a.w*w.y; acc[3][2] += a.w*w.z; acc[3][3] += a.w*w.w;
        }
    }
}

// -------------------- setup kernels ----------------------------------------

__global__ void pre0_kernel(const float* __restrict__ ctx, const int* __restrict__ bh,
                            const float* __restrict__ be, float* __restrict__ A0,
                            int* __restrict__ prev)
{
    int b = blockIdx.x, tid = threadIdx.x; // blockDim 512
    float s = 0.f;
    for (int t = 0; t < TT; ++t) s += ctx[(size_t)b * LDA_CTX + t * 512 + tid];
    A0[b * 1024 + tid] = s * (1.f / 128.f);
    float s2 = 0.f;
    for (int i = 0; i < 8; ++i) s2 += be[bh[b * 8 + i] * 512 + tid];
    A0[b * 1024 + 512 + tid] = s2 * 0.125f;
    if (tid == 0) prev[b] = bh[b * 8 + 7];
}

__global__ void wo2t_kernel(const float* __restrict__ W_o2, float* __restrict__ Wo2t)
{
    int idx = blockIdx.x * 256 + threadIdx.x;
    int k = idx >> 6, n = idx & 63;
    Wo2t[idx] = W_o2[n * 1024 + k];
}

__global__ void uv_kernel(const float* __restrict__ ln_g, const float* __restrict__ ln_b,
                          const float* __restrict__ W_o1, float* __restrict__ uvv)
{
    int idx = blockIdx.x * 256 + threadIdx.x; // 8 blocks -> 2048
    int which = idx >> 10, j = idx & 1023;
    const float* vec = which ? ln_b : ln_g;
    float s = 0.f;
    for (int k = 0; k < 1024; ++k) s += vec[k] * W_o1[(size_t)j * 1536 + k];
    uvv[which * 1024 + j] = s;
}

// hi row-major
__global__ void whi_kernel(const float* __restrict__ src, int ld, int col0,
                           int N, int K, const float* __restrict__ scale,
                           unsigned short* __restrict__ hi)
{
    int idx = blockIdx.x * 256 + threadIdx.x;
    if (idx >= N * K) return;
    int n = idx / K, k = idx - n * K;
    float v = src[(size_t)n * ld + col0 + k];
    if (scale) v *= scale[k];
    hi[idx] = f2bf_rne(v);
}

// lo packed in MFMA fragment order (round-6 verified layout)
__global__ void packlo_kernel(const float* __restrict__ src, int ld, int col0,
                              int N, int K, const float* __restrict__ scale,
                              unsigned short* __restrict__ lo)
{
    int idx = blockIdx.x * 256 + threadIdx.x;
    if (idx >= N * K) return;
    int j = idx & 7;
    int lane = (idx >> 3) & 63;
    int fs = idx >> 9;
    int nKs = K >> 5;
    int nf = fs / nKs, ks = fs - nf * nKs;
    int n = nf * 16 + (lane & 15);
    int k = ks * 32 + (lane >> 4) * 8 + j;
    float v = src[(size_t)n * ld + col0 + k];
    if (scale) v *= scale[k];
    unsigned short h, l;
    split2(v, h, l);
    lo[idx] = l;
}

// row-major hi + lo (activations: h0)
__global__ void wsplit_kernel(const float* __restrict__ src, int src_ld, int col0,
                              int N, int K, const float* __restrict__ scale,
                              unsigned short* __restrict__ hi,
                              unsigned short* __restrict__ lo)
{
    int idx = blockIdx.x * 256 + threadIdx.x;
    if (idx >= N * K) return;
    int n = idx / K, k = idx - n * K;
    float v = src[(size_t)n * src_ld + col0 + k];
    if (scale) v *= scale[k];
    unsigned short h, l;
    split2(v, h, l);
    hi[idx] = h; lo[idx] = l;
}

__global__ void gemm64_kernel(const float* __restrict__ A, int lda, int M,
                              const float* __restrict__ W, int ldw, int K,
                              const float* __restrict__ bias,
                              float* __restrict__ C, int ldc, int act)
{
    __shared__ __align__(16) float At[16 * TS];
    __shared__ __align__(16) float Wt[16 * TS];
    float acc[4][4] = {};
    int b0 = blockIdx.x * 64, n0 = blockIdx.y * 64;
    gemm_tile64(A, lda, M, b0, W, ldw, n0, K, At, Wt, acc);
    int tx = threadIdx.x & 15, ty = threadIdx.x >> 4;
#pragma unroll
    for (int i = 0; i < 4; ++i) {
        int b = b0 + ty * 4 + i;
        if (b >= M) continue;
#pragma unroll
        for (int j = 0; j < 4; ++j) {
            int n = n0 + tx * 4 + j;
            float v = acc[i][j] + (bias ? bias[n] : 0.f);
            if (act == 1) v = tanhf(v);
            C[(size_t)b * ldc + n] = v;
        }
    }
}

__global__ void xbuild0s_kernel(const float* __restrict__ cin0, const float* __restrict__ bpart,
                                const int* __restrict__ prev,
                                unsigned short* __restrict__ xh, unsigned short* __restrict__ xl)
{
    int b = blockIdx.x, tid = threadIdx.x;
    int pb = prev[b];
#pragma unroll
    for (int jj = 0; jj < 4; ++jj) {
        int j = jj * 256 + tid;
        float v = fmaxf(cin0[(size_t)b * 1024 + j] + bpart[(size_t)pb * 1024 + j], 0.f);
        unsigned short h, l;
        split2(v, h, l);
        xh[(size_t)b * 1024 + j] = h;
        xl[(size_t)b * 1024 + j] = l;
    }
}

__global__ void xbuild0_kernel(const float* __restrict__ cin0, const float* __restrict__ bpart,
                               const int* __restrict__ prev, float* __restrict__ x)
{
    int b = blockIdx.x, tid = threadIdx.x;
    int pb = prev[b];
#pragma unroll
    for (int jj = 0; jj < 4; ++jj) {
        int j = jj * 256 + tid;
        x[(size_t)b * 1024 + j] = fmaxf(cin0[(size_t)b * 1024 + j] + bpart[(size_t)pb * 1024 + j], 0.f);
    }
}

// -------------------- fallback fp32 step kernels (round 1) -----------------

__global__ void step_gemms_kernel(
    const float* __restrict__ x, const float* __restrict__ hBase,
    const float* __restrict__ ctx,
    const float* __restrict__ Wih, const float* __restrict__ Whh,
    const float* __restrict__ Win, const float* __restrict__ Wo1,
    const float* __restrict__ b_in, const float* __restrict__ b_o1,
    float* __restrict__ g6, float* __restrict__ cinBase, float* __restrict__ octx,
    int t)
{
    __shared__ __align__(16) float At[16 * TS];
    __shared__ __align__(16) float Wt[16 * TS];
    float acc[4][4] = {};
    const int z = blockIdx.z, b0 = blockIdx.x * 64, n0 = blockIdx.y * 64;
    const float *A, *W, *bias = nullptr;
    float* C;
    int lda, ldw, K;
    if (z < 6) {
        int g = z % 3, s = z / 3;
        A = s ? (hBase + (size_t)(t & 1) * SZ) : x;
        lda = 1024;
        W = (s ? Whh : Wih) + (size_t)(g * 1024) * 1024;
        ldw = 1024; K = 1024;
        C = g6 + (size_t)z * SZ;
    } else if (z == 6) {
        if (t + 1 >= TT) return;
        A = ctx + (size_t)(t + 1) * 512; lda = LDA_CTX;
        W = Win; ldw = 1024; K = 512; bias = b_in;
        C = cinBase + (size_t)((t + 1) & 1) * SZ;
    } else {
        A = ctx + (size_t)t * 512; lda = LDA_CTX;
        W = Wo1 + 1024; ldw = 1536; K = 512; bias = b_o1;
        C = octx;
    }
    gemm_tile64(A, lda, 256, b0, W, ldw, n0, K, At, Wt, acc);
    int tx = threadIdx.x & 15, ty = threadIdx.x >> 4;
#pragma unroll
    for (int i = 0; i < 4; ++i) {
        int b = b0 + ty * 4 + i;
#pragma unroll
        for (int j = 0; j < 4; ++j) {
            int n = n0 + tx * 4 + j;
            float v = acc[i][j];
            if (bias) v += bias[n];
            C[(size_t)b * 1024 + n] = v;
        }
    }
}

__global__ void kb_kernel(const float* __restrict__ hg, const float* __restrict__ Wo1,
                          const float* __restrict__ uv, const float* __restrict__ octx,
                          const float* __restrict__ mbuf, const float* __restrict__ isbuf,
                          float* __restrict__ o)
{
    __shared__ __align__(16) float At[16 * TS];
    __shared__ __align__(16) float Wt[16 * TS];
    float acc[2][4] = {};
    const int b0 = blockIdx.x * 32, n0 = blockIdx.y * 64;
    const int tid = threadIdx.x, tx = tid & 15, ty = tid >> 4;
    const int r = tid >> 2, c0 = (tid & 3) << 2;
    for (int k0 = 0; k0 < 1024; k0 += 16) {
        float4 av = make_float4(0.f, 0.f, 0.f, 0.f);
        if (r < 32) av = *(const float4*)(hg + (size_t)(b0 + r) * 1024 + k0 + c0);
        float4 wv = *(const float4*)(Wo1 + (size_t)(n0 + r) * 1536 + k0 + c0);
        __syncthreads();
        At[(c0+0)*TS + r] = av.x; At[(c0+1)*TS + r] = av.y;
        At[(c0+2)*TS + r] = av.z; At[(c0+3)*TS + r] = av.w;
        Wt[(c0+0)*TS + r] = wv.x; Wt[(c0+1)*TS + r] = wv.y;
        Wt[(c0+2)*TS + r] = wv.z; Wt[(c0+3)*TS + r] = wv.w;
        __syncthreads();
#pragma unroll
        for (int kk = 0; kk < 16; ++kk) {
            float2 a = *(const float2*)(At + kk*TS + ty*2);
            float4 w = *(const float4*)(Wt + kk*TS + tx*4);
            acc[0][0] += a.x*w.x; acc[0][1] += a.x*w.y; acc[0][2] += a.x*w.z; acc[0][3] += a.x*w.w;
            acc[1][0] += a.y*w.x; acc[1][1] += a.y*w.y; acc[1][2] += a.y*w.z; acc[1][3] += a.y*w.w;
        }
    }
#pragma unroll
    for (int i = 0; i < 2; ++i) {
        int b = b0 + ty * 2 + i;
        float m = mbuf[b], is = isbuf[b];
#pragma unroll
        for (int j = 0; j < 4; ++j) {
            int n = n0 + tx * 4 + j;
            float v = (acc[i][j] - m * uv[n]) * is + uv[1024 + n] + octx[(size_t)b * 1024 + n];
            o[(size_t)b * 1024 + n] = fmaxf(v, 0.f);
        }
    }
}

__global__ void gru_ln_kernel(const float* __restrict__ g6,
                              const float* __restrict__ b_ih, const float* __restrict__ b_hh,
                              float* __restrict__ hBase, const float* __restrict__ ln_g,
                              float* __restrict__ hg, float* __restrict__ mbuf,
                              float* __restrict__ isbuf, int t)
{
    __shared__ float rs[256], rq[256];
    int b = blockIdx.x, tid = threadIdx.x;
    const float* hc = hBase + (size_t)(t & 1) * SZ + (size_t)b * 1024;
    float* hnx = hBase + (size_t)((t + 1) & 1) * SZ + (size_t)b * 1024;
    float s = 0.f, q = 0.f;
#pragma unroll
    for (int jj = 0; jj < 4; ++jj) {
        int j = jj * 256 + tid;
        size_t base = (size_t)b * 1024 + j;
        float xr = g6[0 * (size_t)SZ + base] + b_ih[j];
        float xz = g6[1 * (size_t)SZ + base] + b_ih[1024 + j];
        float xn = g6[2 * (size_t)SZ + base] + b_ih[2048 + j];
        float hr = g6[3 * (size_t)SZ + base] + b_hh[j];
        float hz = g6[4 * (size_t)SZ + base] + b_hh[1024 + j];
        float hn = g6[5 * (size_t)SZ + base] + b_hh[2048 + j];
        float r = 1.f / (1.f + expf(-(xr + hr)));
        float z = 1.f / (1.f + expf(-(xz + hz)));
        float nn = tanhf(xn + r * hn);
        float ho = hc[j];
        float hv = (1.f - z) * nn + z * ho;
        hnx[j] = hv;
        hg[base] = hv * ln_g[j];
        s += hv; q += hv * hv;
    }
    rs[tid] = s; rq[tid] = q;
    __syncthreads();
    for (int st = 128; st; st >>= 1) {
        if (tid < st) { rs[tid] += rs[tid + st]; rq[tid] += rq[tid + st]; }
        __syncthreads();
    }
    if (tid == 0) {
        float m = rs[0] * (1.f / 1024.f);
        float var = rq[0] * (1.f / 1024.f) - m * m;
        mbuf[b] = m;
        isbuf[b] = rsqrtf(var + 1e-5f);
    }
}

__global__ void kc_kernel(const float* __restrict__ o, const float* __restrict__ Wo2t,
                          const float* __restrict__ b_o2, const float* __restrict__ cinBase,
                          const float* __restrict__ bpart, float* __restrict__ x,
                          int* __restrict__ prev, float* __restrict__ out, int t)
{
    __shared__ __align__(16) float os[1024];
    __shared__ float red[4][64];
    __shared__ int sidx;
    int b = blockIdx.x, tid = threadIdx.x;
    const float* orow = o + (size_t)b * 1024;
    *(float4*)&os[tid * 4] = *(const float4*)&orow[tid * 4];
    __syncthreads();
    int n = tid & 63, seg = tid >> 6;
    float p = 0.f;
    int k0 = seg * 256;
#pragma unroll 8
    for (int k = 0; k < 256; ++k) p += os[k0 + k] * Wo2t[(size_t)(k0 + k) * 64 + n];
    red[seg][n] = p;
    __syncthreads();
    if (tid < 64) {
        float lg = red[0][tid] + red[1][tid] + red[2][tid] + red[3][tid] + b_o2[tid];
        out[((size_t)b * TT + t) * 64 + tid] = lg;
        float v = lg; int idx = tid;
        for (int off = 32; off; off >>= 1) {
            float ov = __shfl_xor(v, off);
            int oi = __shfl_xor(idx, off);
            if (ov > v || (ov == v && oi < idx)) { v = ov; idx = oi; }
        }
        if (tid == 0) { prev[b] = idx; sidx = idx; }
    }
    __syncthreads();
    if (t + 1 < TT) {
        int pb = sidx;
        const float* cn = cinBase + (size_t)((t + 1) & 1) * SZ + (size_t)b * 1024;
        const float* bp = bpart + (size_t)pb * 1024;
#pragma unroll
        for (int jj = 0; jj < 4; ++jj) {
            int j = jj * 256 + tid;
            x[(size_t)b * 1024 + j] = fmaxf(cn[j] + bp[j], 0.f);
        }
    }
}

__global__ void copy_gb_kernel(const float* g, const float* bb, float* gb)
{
    int idx = blockIdx.x * 256 + threadIdx.x;
    if (idx < 1024) gb[idx] = g[idx];
    else            gb[idx] = bb[idx - 1024];
}

// ---------------------------------------------------------------------------

extern "C" void kernel_launch(void* const* d_in, const int* in_sizes, int n_in,
                              void* d_out, int out_size, void* d_ws, size_t ws_size,
                              hipStream_t stream)
{
    const float* ctx    = (const float*)d_in[0];
    const int*   bh     = (const int*)d_in[1];
    const float* be     = (const float*)d_in[2];
    const float* W_in   = (const float*)d_in[3];
    const float* b_in   = (const float*)d_in[4];
    const float* W_init = (const float*)d_in[5];
    const float* b_init = (const float*)d_in[6];
    const float* W_ih   = (const float*)d_in[7];
    const float* b_ih   = (const float*)d_in[8];
    const float* W_hh   = (const float*)d_in[9];
    const float* b_hh   = (const float*)d_in[10];
    const float* ln_g   = (const float*)d_in[11];
    const float* ln_b   = (const float*)d_in[12];
    const float* W_o1   = (const float*)d_in[13];
    const float* b_o1   = (const float*)d_in[14];
    const float* W_o2   = (const float*)d_in[15];
    const float* b_o2   = (const float*)d_in[16];
    float* out = (float*)d_out;
    float* ws  = (float*)d_ws;

    const bool mfma_path = (ws_size >= 45700000ull);

    if (mfma_path) {
        // ---- round-11 layout (floats) ----
        float* hbuf  = ws;                   // 256x1024 fp32 (in-place h)
        float* cin   = ws + 262144;
        float* octx  = ws + 524288;
        float* g6    = ws + 786432;          // 6 slots; 0..3 reused as o-partials
        float* A0    = g6;                   // setup-only alias
        float* bpart = ws + 2359296;
        float* uvv   = ws + 2424832;
        float* Wo2t  = ws + 2426880;
        float* mbuf  = ws + 2492416;
        float* isbuf = ws + 2492672;
        int*   prev  = (int*)(ws + 2492928);
        unsigned* flags = (unsigned*)(ws + 2493184);   // 8*32*16 = 4096 words
        unsigned* gen   = flags + 4096;                // 8*16 = 128 words
        unsigned short* bf = (unsigned short*)(ws + 2497536);
        unsigned short* wih_hi   = bf;                 // [3072x1024] row-major
        unsigned short* wih_loP  = bf + 3145728;       // packed frags
        unsigned short* whh_hi   = bf + 6291456;
        unsigned short* whh_loP  = bf + 9437184;
        unsigned short* wo1k_hi  = bf + 12582912;      // [1024x1024] ln_g-folded
        unsigned short* wo1k_loP = bf + 13631488;
        unsigned short* wo1c_hi  = bf + 14680064;      // [1024x512]
        unsigned short* wo1c_loP = bf + 15204352;
        unsigned short* wcin_hi  = bf + 15728640;      // [1024x512]
        unsigned short* wcin_loP = bf + 16252928;
        unsigned short* xh       = bf + 16777216;
        unsigned short* xl       = bf + 17039360;
        unsigned short* hh       = bf + 17301504;
        unsigned short* hl       = bf + 17563648;
        // end: 2497536*4 + 17825792*2 = 45,641,728 B

        // ---- setup ----
        hipMemsetAsync((void*)flags, 0, (4096 + 128) * 4, stream);
        pre0_kernel<<<256, 512, 0, stream>>>(ctx, bh, be, A0, prev);
        wo2t_kernel<<<256, 256, 0, stream>>>(W_o2, Wo2t);
        uv_kernel<<<8, 256, 0, stream>>>(ln_g, ln_b, W_o1, uvv);
        gemm64_kernel<<<dim3(4, 16), 256, 0, stream>>>(A0, 1024, 256, W_init, 1024, 1024,
                                                       b_init, hbuf, 1024, 1);
        gemm64_kernel<<<dim3(1, 16), 256, 0, stream>>>(be, 512, 64, W_in + 512, 1024, 512,
                                                       nullptr, bpart, 1024, 0);
        gemm64_kernel<<<dim3(4, 16), 256, 0, stream>>>(ctx, LDA_CTX, 256, W_in, 1024, 512,
                                                       b_in, cin, 1024, 0);
        xbuild0s_kernel<<<256, 256, 0, stream>>>(cin, bpart, prev, xh, xl);
        // weights: hi row-major, lo packed
        whi_kernel<<<12288, 256, 0, stream>>>(W_ih, 1024, 0, 3072, 1024, nullptr, wih_hi);
        packlo_kernel<<<12288, 256, 0, stream>>>(W_ih, 1024, 0, 3072, 1024, nullptr, wih_loP);
        whi_kernel<<<12288, 256, 0, stream>>>(W_hh, 1024, 0, 3072, 1024, nullptr, whh_hi);
        packlo_kernel<<<12288, 256, 0, stream>>>(W_hh, 1024, 0, 3072, 1024, nullptr, whh_loP);
        whi_kernel<<<4096, 256, 0, stream>>>(W_o1, 1536, 0, 1024, 1024, ln_g, wo1k_hi);
        packlo_kernel<<<4096, 256, 0, stream>>>(W_o1, 1536, 0, 1024, 1024, ln_g, wo1k_loP);
        whi_kernel<<<2048, 256, 0, stream>>>(W_o1, 1536, 1024, 1024, 512, nullptr, wo1c_hi);
        packlo_kernel<<<2048, 256, 0, stream>>>(W_o1, 1536, 1024, 1024, 512, nullptr, wo1c_loP);
        whi_kernel<<<2048, 256, 0, stream>>>(W_in, 1024, 0, 1024, 512, nullptr, wcin_hi);
        packlo_kernel<<<2048, 256, 0, stream>>>(W_in, 1024, 0, 1024, 512, nullptr, wcin_loP);
        // h0 split (row-major hi+lo)
        wsplit_kernel<<<1024, 256, 0, stream>>>(hbuf, 1024, 0, 256, 1024, nullptr, hh, hl);

        // ---- whole recurrence: one persistent launch ----
        persist11_kernel<<<256, 256, 0, stream>>>(
            xh, xl, hh, hl, hbuf, ctx,
            wih_hi, wih_loP, whh_hi, whh_loP, wo1k_hi, wo1k_loP,
            wo1c_hi, wo1c_loP, wcin_hi, wcin_loP,
            b_in, b_o1, b_ih, b_hh,
            g6, cin, octx, mbuf, isbuf,
            Wo2t, b_o2, uvv, bpart, prev, out, flags, gen);
    } else {
        // ---- fallback: round-1 fp32 path ----
        float* A0    = ws;
        float* hbuf  = ws + 262144;
        float* hg    = ws + 786432;
        float* x     = ws + 1048576;
        float* cin   = ws + 1310720;
        float* octx  = ws + 1835008;
        float* g6    = ws + 2097152;
        float* obuf  = ws + 3670016;
        float* bpart = ws + 3932160;
        float* uvv   = ws + 3997696;
        float* gb    = ws + 3999744;
        float* Wo2t  = ws + 4001792;
        float* mbuf  = ws + 4067328;
        float* isbuf = ws + 4067584;
        int*   prev  = (int*)(ws + 4067840);

        pre0_kernel<<<256, 512, 0, stream>>>(ctx, bh, be, A0, prev);
        copy_gb_kernel<<<8, 256, 0, stream>>>(ln_g, ln_b, gb);
        wo2t_kernel<<<256, 256, 0, stream>>>(W_o2, Wo2t);
        gemm64_kernel<<<dim3(4, 16), 256, 0, stream>>>(A0, 1024, 256, W_init, 1024, 1024,
                                                       b_init, hbuf, 1024, 1);
        gemm64_kernel<<<dim3(1, 16), 256, 0, stream>>>(be, 512, 64, W_in + 512, 1024, 512,
                                                       nullptr, bpart, 1024, 0);
        gemm64_kernel<<<dim3(1, 16), 256, 0, stream>>>(gb, 1024, 2, W_o1, 1536, 1024,
                                                       nullptr, uvv, 1024, 0);
        gemm64_kernel<<<dim3(4, 16), 256, 0, stream>>>(ctx, LDA_CTX, 256, W_in, 1024, 512,
                                                       b_in, cin, 1024, 0);
        xbuild0_kernel<<<256, 256, 0, stream>>>(cin, bpart, prev, x);

        for (int t = 0; t < TT; ++t) {
            step_gemms_kernel<<<dim3(4, 16, 8), 256, 0, stream>>>(
                x, hbuf, ctx, W_ih, W_hh, W_in, W_o1, b_in, b_o1, g6, cin, octx, t);
            gru_ln_kernel<<<256, 256, 0, stream>>>(g6, b_ih, b_hh, hbuf, ln_g, hg,
                                                   mbuf, isbuf, t);
            kb_kernel<<<dim3(8, 16), 256, 0, stream>>>(hg, W_o1, uvv, octx, mbuf, isbuf, obuf);
            kc_kernel<<<256, 256, 0, stream>>>(obuf, Wo2t, b_o2, cin, bpart, x, prev, out, t);
        }
    }
}

// Round 12
// 7334.503 us; speedup vs baseline: 3.4632x; 3.4632x over previous
//
#include <hip/hip_runtime.h>
#include <hip/hip_bf16.h>

// ---------------------------------------------------------------------------
// AutoregressiveBeamDecoder: B=256, T=128, D=512, H=1024, NB=64, HH=8
// Round 12: round-7 skeleton (4 launches/step, proven 7.91 ms) with B-lo
// moved out of LDS: read as packed MFMA fragments direct from global
// (round-11 verified layout; no cross-block redundancy in this grid).
// Per K-iter: LDS writes 24->16 KB, LDS reads 48->32 KB.
//  - gates12: grid 256 (bid = tile*8 + z); z<6 gate GEMMs use core12b
//    (A-hi/lo + B-hi in LDS, B-lo packed global); z=6/7 ctx GEMMs use
//    fp32-A core (round-10 verified, off critical path).
//  - gru: round-7 gru_ln6 (unchanged). kb12: K-split 4, core12b.
//  - kc12: round-7 kc7 minus ctx-split.
// C = Ahi@Bhi + Ahi@Blo + Alo@Bhi (3x mfma_f32_16x16x32_bf16, fp32 accum)
// ---------------------------------------------------------------------------

#define TS 68          // fp32 LDS row stride (fallback path only)
#define LDPA 40        // bf16 LDS row stride (shorts): 80 B
constexpr int SZ = 262144;     // 256*1024
constexpr int TT = 128;        // T
constexpr int LDA_CTX = 65536; // T*D

typedef __attribute__((ext_vector_type(8))) short short8_t;
typedef __attribute__((ext_vector_type(4))) float f32x4;

// ---------------- bf16 split helpers (bit-level, RNE) ----------------------

__device__ __forceinline__ unsigned short f2bf_rne(float v) {
    unsigned u = __float_as_uint(v);
    unsigned r = u + 0x7fffu + ((u >> 16) & 1u);
    return (unsigned short)(r >> 16);
}
__device__ __forceinline__ float bfbits2f(unsigned short h) {
    return __uint_as_float(((unsigned)h) << 16);
}
__device__ __forceinline__ void split2(float v, unsigned short& h, unsigned short& l) {
    h = f2bf_rne(v);
    l = f2bf_rne(v - bfbits2f(h));
}
__device__ __forceinline__ void splitA8(const float4& v0, const float4& v1,
                                        short8_t& hi, short8_t& lo) {
    unsigned short h[8], l[8];
    split2(v0.x, h[0], l[0]); split2(v0.y, h[1], l[1]);
    split2(v0.z, h[2], l[2]); split2(v0.w, h[3], l[3]);
    split2(v1.x, h[4], l[4]); split2(v1.y, h[5], l[5]);
    split2(v1.z, h[6], l[6]); split2(v1.w, h[7], l[7]);
    hi = short8_t{(short)h[0],(short)h[1],(short)h[2],(short)h[3],
                  (short)h[4],(short)h[5],(short)h[6],(short)h[7]};
    lo = short8_t{(short)l[0],(short)l[1],(short)l[2],(short)l[3],
                  (short)l[4],(short)l[5],(short)l[6],(short)l[7]};
}

// ---------------- core12b: A bf16 presplit, B-hi LDS, B-lo packed global ---
// block 64(M) x 128(N), 256 thr = 4 waves; wave (wr=wid>>1, wc=wid&1) owns
// 32x64 = 2 A-frags x 4 B-frags. BK=32, double-buffered, 1 barrier/iter.
// sm shorts/buf: Ah[64*40]=2560 | Al 2560 | Bh[128*40]=5120 -> 10240, x2.
// BlP: packed frags, frag nf at BlP + (nf*nKs + ks)*512 + lane*8.

__device__ __forceinline__ void core12b(
    const unsigned short* __restrict__ Ah, const unsigned short* __restrict__ Al,
    int lda, int b0,
    const unsigned short* __restrict__ Bh, int ldb,   // pre-offset to row n0
    const unsigned short* __restrict__ BlP, int nKs, int ksbase, int nfb,
    int nIter, unsigned short* sm, f32x4 acc[2][4])
{
    const int tid = threadIdx.x, lane = tid & 63, wid = tid >> 6;
    const int wr = wid >> 1, wc = wid & 1;
    const int l15 = lane & 15, kg = (lane >> 4) * 8;
    const int arow = tid >> 2, acol = (tid & 3) * 8;   // A: 4 thr/row
    const int brow = tid >> 1, bcol = (tid & 1) * 16;  // B: 2 thr/row, 16 shorts

    const int ALO = 2560, BHI = 5120, BUF = 10240;

    const unsigned short* gAh = Ah + (size_t)(b0 + arow) * lda + ksbase * 32 + acol;
    const unsigned short* gAl = Al + (size_t)(b0 + arow) * lda + ksbase * 32 + acol;
    const unsigned short* gBh = Bh + (size_t)brow * ldb + ksbase * 32 + bcol;
    const unsigned short* pBl[4];
#pragma unroll
    for (int ni = 0; ni < 4; ++ni)
        pBl[ni] = BlP + ((size_t)(nfb + ni) * nKs + ksbase) * 512 + lane * 8;

    short8_t cBl[4], nBl[4];
    {
        short8_t a_h = *(const short8_t*)gAh;
        short8_t a_l = *(const short8_t*)gAl;
        short8_t b0h = *(const short8_t*)gBh;
        short8_t b1h = *(const short8_t*)(gBh + 8);
        *(short8_t*)&sm[arow * LDPA + acol]            = a_h;
        *(short8_t*)&sm[ALO + arow * LDPA + acol]      = a_l;
        *(short8_t*)&sm[BHI + brow * LDPA + bcol]      = b0h;
        *(short8_t*)&sm[BHI + brow * LDPA + bcol + 8]  = b1h;
#pragma unroll
        for (int ni = 0; ni < 4; ++ni) cBl[ni] = *(const short8_t*)pBl[ni];
    }
    __syncthreads();

    int cur = 0;
    const int aro = (wr * 32 + l15) * LDPA + kg;
    for (int i = 0; i < nIter; ++i) {
        short8_t a_h, a_l, b0h, b1h;
        if (i + 1 < nIter) {               // prefetch next tile (under compute)
            const int ko = (i + 1) * 32;
            a_h = *(const short8_t*)(gAh + ko);
            a_l = *(const short8_t*)(gAl + ko);
            b0h = *(const short8_t*)(gBh + ko);
            b1h = *(const short8_t*)(gBh + ko + 8);
#pragma unroll
            for (int ni = 0; ni < 4; ++ni)
                nBl[ni] = *(const short8_t*)(pBl[ni] + (size_t)(i + 1) * 512);
        }
        const unsigned short* S = sm + cur * BUF;
        short8_t afh[2], afl[2];
#pragma unroll
        for (int mi = 0; mi < 2; ++mi) {
            afh[mi] = *(const short8_t*)&S[aro + mi * 16 * LDPA];
            afl[mi] = *(const short8_t*)&S[ALO + aro + mi * 16 * LDPA];
        }
#pragma unroll
        for (int ni = 0; ni < 4; ++ni) {
            short8_t b_h = *(const short8_t*)&S[BHI + (wc * 64 + ni * 16 + l15) * LDPA + kg];
#pragma unroll
            for (int mi = 0; mi < 2; ++mi) {
                acc[mi][ni] = __builtin_amdgcn_mfma_f32_16x16x32_bf16(afh[mi], b_h, acc[mi][ni], 0, 0, 0);
                acc[mi][ni] = __builtin_amdgcn_mfma_f32_16x16x32_bf16(afh[mi], cBl[ni], acc[mi][ni], 0, 0, 0);
                acc[mi][ni] = __builtin_amdgcn_mfma_f32_16x16x32_bf16(afl[mi], b_h, acc[mi][ni], 0, 0, 0);
            }
        }
        if (i + 1 < nIter) {
            unsigned short* N_ = sm + (cur ^ 1) * BUF;
            *(short8_t*)&N_[arow * LDPA + acol]           = a_h;
            *(short8_t*)&N_[ALO + arow * LDPA + acol]     = a_l;
            *(short8_t*)&N_[BHI + brow * LDPA + bcol]     = b0h;
            *(short8_t*)&N_[BHI + brow * LDPA + bcol + 8] = b1h;
        }
        __syncthreads();
        cur ^= 1;
#pragma unroll
        for (int ni = 0; ni < 4; ++ni) cBl[ni] = nBl[ni];
    }
}

// ---------------- core9: A fp32 (in-register split), B hi/lo in LDS --------
// Used only for the two ctx GEMMs (z=6,7), K=512. Round-10 verified.

__device__ __forceinline__ void mfma_core9(
    const float* __restrict__ A, int lda, int b0,
    const unsigned short* __restrict__ Bh, const unsigned short* __restrict__ Bl,
    int ldb, int n0, int k0base, int nIter,
    unsigned short* sm, f32x4 acc[2][4])
{
    const int tid = threadIdx.x, lane = tid & 63, wid = tid >> 6;
    const int wr = wid >> 1, wc = wid & 1;
    const int l15 = lane & 15, kg = (lane >> 4) * 8;
    const int arow = tid >> 2, acol = (tid & 3) * 8;
    const int brow = tid >> 1, bcol = (tid & 1) * 16;

    const int AOFF = 2560, BHOFF = 5120, BLOFF = 10240, BUF = 15360;

    const float* gA = A + (size_t)(b0 + arow) * lda + k0base + acol;
    const unsigned short* gBh = Bh + (size_t)(n0 + brow) * ldb + k0base + bcol;
    const unsigned short* gBl = Bl + (size_t)(n0 + brow) * ldb + k0base + bcol;

    {
        float4 a0 = *(const float4*)gA;
        float4 a1 = *(const float4*)(gA + 4);
        short8_t ah, al;
        splitA8(a0, a1, ah, al);
        short8_t bh0 = *(const short8_t*)gBh;
        short8_t bh1 = *(const short8_t*)(gBh + 8);
        short8_t bl0 = *(const short8_t*)gBl;
        short8_t bl1 = *(const short8_t*)(gBl + 8);
        *(short8_t*)&sm[arow * LDPA + acol]              = ah;
        *(short8_t*)&sm[AOFF + arow * LDPA + acol]       = al;
        *(short8_t*)&sm[BHOFF + brow * LDPA + bcol]      = bh0;
        *(short8_t*)&sm[BHOFF + brow * LDPA + bcol + 8]  = bh1;
        *(short8_t*)&sm[BLOFF + brow * LDPA + bcol]      = bl0;
        *(short8_t*)&sm[BLOFF + brow * LDPA + bcol + 8]  = bl1;
    }
    __syncthreads();

    int cur = 0;
    const int aro = (wr * 32 + l15) * LDPA + kg;
    for (int i = 0; i < nIter; ++i) {
        float4 a0, a1;
        short8_t bh0, bh1, bl0, bl1;
        if (i + 1 < nIter) {
            const int ko = (i + 1) * 32;
            a0 = *(const float4*)(gA + ko);
            a1 = *(const float4*)(gA + ko + 4);
            bh0 = *(const short8_t*)(gBh + ko);
            bh1 = *(const short8_t*)(gBh + ko + 8);
            bl0 = *(const short8_t*)(gBl + ko);
            bl1 = *(const short8_t*)(gBl + ko + 8);
        }
        const unsigned short* S = sm + cur * BUF;
        short8_t afh[2], afl[2];
#pragma unroll
        for (int mi = 0; mi < 2; ++mi) {
            afh[mi] = *(const short8_t*)&S[aro + mi * 16 * LDPA];
            afl[mi] = *(const short8_t*)&S[AOFF + aro + mi * 16 * LDPA];
        }
#pragma unroll
        for (int ni = 0; ni < 4; ++ni) {
            const int bro = (wc * 64 + ni * 16 + l15) * LDPA + kg;
            short8_t b_h = *(const short8_t*)&S[BHOFF + bro];
            short8_t b_l = *(const short8_t*)&S[BLOFF + bro];
#pragma unroll
            for (int mi = 0; mi < 2; ++mi) {
                acc[mi][ni] = __builtin_amdgcn_mfma_f32_16x16x32_bf16(afh[mi], b_h, acc[mi][ni], 0, 0, 0);
                acc[mi][ni] = __builtin_amdgcn_mfma_f32_16x16x32_bf16(afh[mi], b_l, acc[mi][ni], 0, 0, 0);
                acc[mi][ni] = __builtin_amdgcn_mfma_f32_16x16x32_bf16(afl[mi], b_h, acc[mi][ni], 0, 0, 0);
            }
        }
        if (i + 1 < nIter) {
            short8_t ah, al;
            splitA8(a0, a1, ah, al);
            unsigned short* N_ = sm + (cur ^ 1) * BUF;
            *(short8_t*)&N_[arow * LDPA + acol]             = ah;
            *(short8_t*)&N_[AOFF + arow * LDPA + acol]      = al;
            *(short8_t*)&N_[BHOFF + brow * LDPA + bcol]     = bh0;
            *(short8_t*)&N_[BHOFF + brow * LDPA + bcol + 8] = bh1;
            *(short8_t*)&N_[BLOFF + brow * LDPA + bcol]     = bl0;
            *(short8_t*)&N_[BLOFF + brow * LDPA + bcol + 8] = bl1;
        }
        __syncthreads();
        cur ^= 1;
    }
}

// ---------------- fp32 tiled GEMM core (setup + fallback) ------------------

__device__ __forceinline__ void gemm_tile64(
    const float* __restrict__ A, int lda, int Mlim, int b0,
    const float* __restrict__ W, int ldw, int n0, int K,
    float* At, float* Wt, float acc[4][4])
{
    const int tid = threadIdx.x;
    const int tx = tid & 15, ty = tid >> 4;
    const int r = tid >> 2, c0 = (tid & 3) << 2;
    for (int k0 = 0; k0 < K; k0 += 16) {
        float4 av = make_float4(0.f, 0.f, 0.f, 0.f);
        if (b0 + r < Mlim)
            av = *(const float4*)(A + (size_t)(b0 + r) * lda + k0 + c0);
        float4 wv = *(const float4*)(W + (size_t)(n0 + r) * ldw + k0 + c0);
        __syncthreads();
        At[(c0+0)*TS + r] = av.x; At[(c0+1)*TS + r] = av.y;
        At[(c0+2)*TS + r] = av.z; At[(c0+3)*TS + r] = av.w;
        Wt[(c0+0)*TS + r] = wv.x; Wt[(c0+1)*TS + r] = wv.y;
        Wt[(c0+2)*TS + r] = wv.z; Wt[(c0+3)*TS + r] = wv.w;
        __syncthreads();
#pragma unroll
        for (int kk = 0; kk < 16; ++kk) {
            float4 a = *(const float4*)(At + kk*TS + ty*4);
            float4 w = *(const float4*)(Wt + kk*TS + tx*4);
            acc[0][0] += a.x*w.x; acc[0][1] += a.x*w.y; acc[0][2] += a.x*w.z; acc[0][3] += a.x*w.w;
            acc[1][0] += a.y*w.x; acc[1][1] += a.y*w.y; acc[1][2] += a.y*w.z; acc[1][3] += a.y*w.w;
            acc[2][0] += a.z*w.x; acc[2][1] += a.z*w.y; acc[2][2] += a.z*w.z; acc[2][3] += a.z*w.w;
            acc[3][0] += a.w*w.x; acc[3][1] += a.w*w.y; acc[3][2] += a.w*w.z; acc[3][3] += a.w*w.w;
        }
    }
}

// -------------------- setup kernels ----------------------------------------

__global__ void pre0_kernel(const float* __restrict__ ctx, const int* __restrict__ bh,
                            const float* __restrict__ be, float* __restrict__ A0,
                            int* __restrict__ prev)
{
    int b = blockIdx.x, tid = threadIdx.x; // blockDim 512
    float s = 0.f;
    for (int t = 0; t < TT; ++t) s += ctx[(size_t)b * LDA_CTX + t * 512 + tid];
    A0[b * 1024 + tid] = s * (1.f / 128.f);
    float s2 = 0.f;
    for (int i = 0; i < 8; ++i) s2 += be[bh[b * 8 + i] * 512 + tid];
    A0[b * 1024 + 512 + tid] = s2 * 0.125f;
    if (tid == 0) prev[b] = bh[b * 8 + 7];
}

__global__ void wo2t_kernel(const float* __restrict__ W_o2, float* __restrict__ Wo2t)
{
    int idx = blockIdx.x * 256 + threadIdx.x;
    int k = idx >> 6, n = idx & 63;
    Wo2t[idx] = W_o2[n * 1024 + k];
}

__global__ void uv_kernel(const float* __restrict__ ln_g, const float* __restrict__ ln_b,
                          const float* __restrict__ W_o1, float* __restrict__ uvv)
{
    int idx = blockIdx.x * 256 + threadIdx.x; // 8 blocks -> 2048
    int which = idx >> 10, j = idx & 1023;
    const float* vec = which ? ln_b : ln_g;
    float s = 0.f;
    for (int k = 0; k < 1024; ++k) s += vec[k] * W_o1[(size_t)j * 1536 + k];
    uvv[which * 1024 + j] = s;
}

// hi row-major
__global__ void whi_kernel(const float* __restrict__ src, int ld, int col0,
                           int N, int K, const float* __restrict__ scale,
                           unsigned short* __restrict__ hi)
{
    int idx = blockIdx.x * 256 + threadIdx.x;
    if (idx >= N * K) return;
    int n = idx / K, k = idx - n * K;
    float v = src[(size_t)n * ld + col0 + k];
    if (scale) v *= scale[k];
    hi[idx] = f2bf_rne(v);
}

// lo packed in MFMA fragment order (round-6/11 verified layout)
__global__ void packlo_kernel(const float* __restrict__ src, int ld, int col0,
                              int N, int K, const float* __restrict__ scale,
                              unsigned short* __restrict__ lo)
{
    int idx = blockIdx.x * 256 + threadIdx.x;
    if (idx >= N * K) return;
    int j = idx & 7;
    int lane = (idx >> 3) & 63;
    int fs = idx >> 9;
    int nKs = K >> 5;
    int nf = fs / nKs, ks = fs - nf * nKs;
    int n = nf * 16 + (lane & 15);
    int k = ks * 32 + (lane >> 4) * 8 + j;
    float v = src[(size_t)n * ld + col0 + k];
    if (scale) v *= scale[k];
    unsigned short h, l;
    split2(v, h, l);
    lo[idx] = l;
}

// row-major hi + lo
__global__ void wsplit_kernel(const float* __restrict__ src, int src_ld, int col0,
                              int N, int K, const float* __restrict__ scale,
                              unsigned short* __restrict__ hi,
                              unsigned short* __restrict__ lo)
{
    int idx = blockIdx.x * 256 + threadIdx.x;
    if (idx >= N * K) return;
    int n = idx / K, k = idx - n * K;
    float v = src[(size_t)n * src_ld + col0 + k];
    if (scale) v *= scale[k];
    unsigned short h, l;
    split2(v, h, l);
    hi[idx] = h; lo[idx] = l;
}

__global__ void gemm64_kernel(const float* __restrict__ A, int lda, int M,
                              const float* __restrict__ W, int ldw, int K,
                              const float* __restrict__ bias,
                              float* __restrict__ C, int ldc, int act)
{
    __shared__ __align__(16) float At[16 * TS];
    __shared__ __align__(16) float Wt[16 * TS];
    float acc[4][4] = {};
    int b0 = blockIdx.x * 64, n0 = blockIdx.y * 64;
    gemm_tile64(A, lda, M, b0, W, ldw, n0, K, At, Wt, acc);
    int tx = threadIdx.x & 15, ty = threadIdx.x >> 4;
#pragma unroll
    for (int i = 0; i < 4; ++i) {
        int b = b0 + ty * 4 + i;
        if (b >= M) continue;
#pragma unroll
        for (int j = 0; j < 4; ++j) {
            int n = n0 + tx * 4 + j;
            float v = acc[i][j] + (bias ? bias[n] : 0.f);
            if (act == 1) v = tanhf(v);
            C[(size_t)b * ldc + n] = v;
        }
    }
}

__global__ void xbuild0s_kernel(const float* __restrict__ cin0, const float* __restrict__ bpart,
                                const int* __restrict__ prev,
                                unsigned short* __restrict__ xh, unsigned short* __restrict__ xl)
{
    int b = blockIdx.x, tid = threadIdx.x;
    int pb = prev[b];
#pragma unroll
    for (int jj = 0; jj < 4; ++jj) {
        int j = jj * 256 + tid;
        float v = fmaxf(cin0[(size_t)b * 1024 + j] + bpart[(size_t)pb * 1024 + j], 0.f);
        unsigned short h, l;
        split2(v, h, l);
        xh[(size_t)b * 1024 + j] = h;
        xl[(size_t)b * 1024 + j] = l;
    }
}

__global__ void xbuild0_kernel(const float* __restrict__ cin0, const float* __restrict__ bpart,
                               const int* __restrict__ prev, float* __restrict__ x)
{
    int b = blockIdx.x, tid = threadIdx.x;
    int pb = prev[b];
#pragma unroll
    for (int jj = 0; jj < 4; ++jj) {
        int j = jj * 256 + tid;
        x[(size_t)b * 1024 + j] = fmaxf(cin0[(size_t)b * 1024 + j] + bpart[(size_t)pb * 1024 + j], 0.f);
    }
}

// -------------------- per-step kernels (round 12) --------------------------

// Fused 8-way GEMM; grid 256: bid = tile*8 + z (XCD class = z).
__global__ __launch_bounds__(256) void gates12_kernel(
    const unsigned short* __restrict__ xh, const unsigned short* __restrict__ xl,
    const unsigned short* __restrict__ hh, const unsigned short* __restrict__ hl,
    const float* __restrict__ ctx,
    const unsigned short* __restrict__ wih_hi, const unsigned short* __restrict__ wih_loP,
    const unsigned short* __restrict__ whh_hi, const unsigned short* __restrict__ whh_loP,
    const unsigned short* __restrict__ wcin_hi, const unsigned short* __restrict__ wcin_lo,
    const unsigned short* __restrict__ wo1c_hi, const unsigned short* __restrict__ wo1c_lo,
    const float* __restrict__ b_in, const float* __restrict__ b_o1,
    float* __restrict__ g6, float* __restrict__ cin, float* __restrict__ octx,
    int t)
{
    const int bid = blockIdx.x;
    const int z = bid & 7;
    const int tile = bid >> 3;
    const int tm = tile & 3, tn = tile >> 2;
    if (z == 6 && t + 1 >= TT) return;
    const int b0 = tm * 64, n0 = tn * 128;

    __shared__ __align__(16) unsigned short sm[2 * 15360];
    f32x4 acc[2][4] = {};
    const float* bias = nullptr;
    float* C;
    const int wid = threadIdx.x >> 6, wc = wid & 1;

    if (z < 6) {
        int g = z % 3, s = z / 3;
        const unsigned short* Ah = s ? hh : xh;
        const unsigned short* Al = s ? hl : xl;
        const unsigned short* Bh = (s ? whh_hi : wih_hi) + (size_t)(g * 1024 + n0) * 1024;
        const unsigned short* BlP = s ? whh_loP : wih_loP;
        const int nfb = g * 64 + (n0 >> 4) + wc * 4;
        C = g6 + (size_t)z * SZ;
        core12b(Ah, Al, 1024, b0, Bh, 1024, BlP, 32, 0, nfb, 32, sm, acc);
    } else if (z == 6) {
        const float* A = ctx + (size_t)(t + 1) * 512;
        bias = b_in; C = cin;
        mfma_core9(A, LDA_CTX, b0, wcin_hi, wcin_lo, 512, n0, 0, 16, sm, acc);
    } else {
        const float* A = ctx + (size_t)t * 512;
        bias = b_o1; C = octx;
        mfma_core9(A, LDA_CTX, b0, wo1c_hi, wo1c_lo, 512, n0, 0, 16, sm, acc);
    }

    const int lane = threadIdx.x & 63;
    const int wr = wid >> 1;
    const int l15 = lane & 15, g4 = (lane >> 4) * 4;
#pragma unroll
    for (int mi = 0; mi < 2; ++mi) {
#pragma unroll
        for (int ni = 0; ni < 4; ++ni) {
            int col = n0 + wc * 64 + ni * 16 + l15;
            float bv = bias ? bias[col] : 0.f;
#pragma unroll
            for (int r = 0; r < 4; ++r) {
                int row = b0 + wr * 32 + mi * 16 + g4 + r;
                C[(size_t)row * 1024 + col] = acc[mi][ni][r] + bv;
            }
        }
    }
}

// o-GEMM raw partials, K-split 4 into g6 slots 0..3; grid 128:
// bid = tm*32 + tn*4 + p
__global__ __launch_bounds__(256) void kb12_kernel(
    const unsigned short* __restrict__ hh, const unsigned short* __restrict__ hl,
    const unsigned short* __restrict__ wo1k_hi, const unsigned short* __restrict__ wo1k_loP,
    float* __restrict__ g6)
{
    const int bid = blockIdx.x;
    const int tm = bid >> 5, tn = (bid >> 2) & 7, p = bid & 3;
    const int b0 = tm * 64, n0 = tn * 128;
    const int wid = threadIdx.x >> 6, wc = wid & 1;

    __shared__ __align__(16) unsigned short sm[2 * 10240];
    f32x4 acc[2][4] = {};
    core12b(hh, hl, 1024, b0, wo1k_hi + (size_t)n0 * 1024, 1024,
            wo1k_loP, 32, p * 8, (n0 >> 4) + wc * 4, 8, sm, acc);

    float* C = g6 + (size_t)p * SZ;
    const int lane = threadIdx.x & 63;
    const int wr = wid >> 1;
    const int l15 = lane & 15, g4 = (lane >> 4) * 4;
#pragma unroll
    for (int mi = 0; mi < 2; ++mi) {
#pragma unroll
        for (int ni = 0; ni < 4; ++ni) {
            int col = n0 + wc * 64 + ni * 16 + l15;
#pragma unroll
            for (int r = 0; r < 4; ++r) {
                int row = b0 + wr * 32 + mi * 16 + g4 + r;
                C[(size_t)row * 1024 + col] = acc[mi][ni][r];
            }
        }
    }
}

// GRU combine + LN stats; writes h fp32 in-place + split h
__global__ void gru_ln6_kernel(const float* __restrict__ g6,
                               const float* __restrict__ b_ih, const float* __restrict__ b_hh,
                               float* __restrict__ h,
                               unsigned short* __restrict__ hh, unsigned short* __restrict__ hl,
                               float* __restrict__ mbuf, float* __restrict__ isbuf)
{
    __shared__ float ls[4], lq[4];
    int b = blockIdx.x, tid = threadIdx.x;
    float s = 0.f, q = 0.f;
#pragma unroll
    for (int jj = 0; jj < 4; ++jj) {
        int j = jj * 256 + tid;
        size_t base = (size_t)b * 1024 + j;
        float xr = g6[0 * (size_t)SZ + base] + b_ih[j];
        float xz = g6[1 * (size_t)SZ + base] + b_ih[1024 + j];
        float xn = g6[2 * (size_t)SZ + base] + b_ih[2048 + j];
        float hr = g6[3 * (size_t)SZ + base] + b_hh[j];
        float hz = g6[4 * (size_t)SZ + base] + b_hh[1024 + j];
        float hn = g6[5 * (size_t)SZ + base] + b_hh[2048 + j];
        float r = 1.f / (1.f + expf(-(xr + hr)));
        float z = 1.f / (1.f + expf(-(xz + hz)));
        float nn = tanhf(xn + r * hn);
        float ho = h[base];
        float hv = (1.f - z) * nn + z * ho;
        h[base] = hv;
        unsigned short a, c;
        split2(hv, a, c); hh[base] = a; hl[base] = c;
        s += hv; q += hv * hv;
    }
    for (int off = 32; off; off >>= 1) {
        s += __shfl_down(s, off);
        q += __shfl_down(q, off);
    }
    int lane = tid & 63, w = tid >> 6;
    if (lane == 0) { ls[w] = s; lq[w] = q; }
    __syncthreads();
    if (tid == 0) {
        float S = ls[0] + ls[1] + ls[2] + ls[3];
        float Q = lq[0] + lq[1] + lq[2] + lq[3];
        float m = S * (1.f / 1024.f);
        mbuf[b] = m;
        isbuf[b] = rsqrtf(Q * (1.f / 1024.f) - m * m + 1e-5f);
    }
}

// partial-sum + LN epilogue + logits + argmax + x split build
// 64 blocks x 256 thr, 4 rows each
__global__ void kc12_kernel(const float* __restrict__ g6,
                            const float* __restrict__ Wo2t, const float* __restrict__ b_o2,
                            const float* __restrict__ uv, const float* __restrict__ octx,
                            const float* __restrict__ mbuf, const float* __restrict__ isbuf,
                            const float* __restrict__ cin, const float* __restrict__ bpart,
                            unsigned short* __restrict__ xh, unsigned short* __restrict__ xl,
                            int* __restrict__ prev, float* __restrict__ out, int t)
{
    __shared__ __align__(16) float os[4][1024];
    __shared__ float red[4][4][64];
    __shared__ int sidx[4];
    const int b0 = blockIdx.x * 4, tid = threadIdx.x;

#pragma unroll
    for (int i = 0; i < 4; ++i) {
        int f = tid + i * 256;
        int r = f >> 8, c4 = (f & 255) << 2;
        size_t base = (size_t)(b0 + r) * 1024 + c4;
        float4 p0 = *(const float4*)(g6 + base);
        float4 p1 = *(const float4*)(g6 + (size_t)SZ + base);
        float4 p2 = *(const float4*)(g6 + 2 * (size_t)SZ + base);
        float4 p3 = *(const float4*)(g6 + 3 * (size_t)SZ + base);
        float4 oc = *(const float4*)(octx + base);
        float4 u4 = *(const float4*)(uv + c4);
        float4 v4 = *(const float4*)(uv + 1024 + c4);
        float m = mbuf[b0 + r], is = isbuf[b0 + r];
        float4 o4;
        o4.x = fmaxf((p0.x + p1.x + p2.x + p3.x - m * u4.x) * is + v4.x + oc.x, 0.f);
        o4.y = fmaxf((p0.y + p1.y + p2.y + p3.y - m * u4.y) * is + v4.y + oc.y, 0.f);
        o4.z = fmaxf((p0.z + p1.z + p2.z + p3.z - m * u4.z) * is + v4.z + oc.z, 0.f);
        o4.w = fmaxf((p0.w + p1.w + p2.w + p3.w - m * u4.w) * is + v4.w + oc.w, 0.f);
        *(float4*)&os[r][c4] = o4;
    }
    __syncthreads();

    {
        int n = tid & 63, seg = tid >> 6;
        float p0 = 0.f, p1 = 0.f, p2 = 0.f, p3 = 0.f;
        int k0 = seg * 256;
        for (int k = k0; k < k0 + 256; ++k) {
            float w = Wo2t[(size_t)k * 64 + n];
            p0 += os[0][k] * w; p1 += os[1][k] * w;
            p2 += os[2][k] * w; p3 += os[3][k] * w;
        }
        red[0][seg][n] = p0; red[1][seg][n] = p1;
        red[2][seg][n] = p2; red[3][seg][n] = p3;
    }
    __syncthreads();

    {
        int r = tid >> 6, n = tid & 63;
        float lg = red[r][0][n] + red[r][1][n] + red[r][2][n] + red[r][3][n] + b_o2[n];
        out[(size_t)(b0 + r) * (TT * 64) + t * 64 + n] = lg;
        float v = lg; int idx = n;
        for (int off = 32; off; off >>= 1) {
            float ov = __shfl_xor(v, off);
            int oi = __shfl_xor(idx, off);
            if (ov > v || (ov == v && oi < idx)) { v = ov; idx = oi; }
        }
        if (n == 0) { prev[b0 + r] = idx; sidx[r] = idx; }
    }
    __syncthreads();

    if (t + 1 < TT) {
#pragma unroll
        for (int i = 0; i < 16; ++i) {
            int idx = tid + i * 256;       // 0..4095
            int r = idx >> 10, j = idx & 1023;
            float v = fmaxf(cin[(size_t)(b0 + r) * 1024 + j] +
                            bpart[(size_t)sidx[r] * 1024 + j], 0.f);
            unsigned short h, l;
            split2(v, h, l);
            xh[(size_t)(b0 + r) * 1024 + j] = h;
            xl[(size_t)(b0 + r) * 1024 + j] = l;
        }
    }
}

// -------------------- fallback fp32 step kernels (round 1) -----------------

__global__ void step_gemms_kernel(
    const float* __restrict__ x, const float* __restrict__ hBase,
    const float* __restrict__ ctx,
    const float* __restrict__ Wih, const float* __restrict__ Whh,
    const float* __restrict__ Win, const float* __restrict__ Wo1,
    const float* __restrict__ b_in, const float* __restrict__ b_o1,
    float* __restrict__ g6, float* __restrict__ cinBase, float* __restrict__ octx,
    int t)
{
    __shared__ __align__(16) float At[16 * TS];
    __shared__ __align__(16) float Wt[16 * TS];
    float acc[4][4] = {};
    const int z = blockIdx.z, b0 = blockIdx.x * 64, n0 = blockIdx.y * 64;
    const float *A, *W, *bias = nullptr;
    float* C;
    int lda, ldw, K;
    if (z < 6) {
        int g = z % 3, s = z / 3;
        A = s ? (hBase + (size_t)(t & 1) * SZ) : x;
        lda = 1024;
        W = (s ? Whh : Wih) + (size_t)(g * 1024) * 1024;
        ldw = 1024; K = 1024;
        C = g6 + (size_t)z * SZ;
    } else if (z == 6) {
        if (t + 1 >= TT) return;
        A = ctx + (size_t)(t + 1) * 512; lda = LDA_CTX;
        W = Win; ldw = 1024; K = 512; bias = b_in;
        C = cinBase + (size_t)((t + 1) & 1) * SZ;
    } else {
        A = ctx + (size_t)t * 512; lda = LDA_CTX;
        W = Wo1 + 1024; ldw = 1536; K = 512; bias = b_o1;
        C = octx;
    }
    gemm_tile64(A, lda, 256, b0, W, ldw, n0, K, At, Wt, acc);
    int tx = threadIdx.x & 15, ty = threadIdx.x >> 4;
#pragma unroll
    for (int i = 0; i < 4; ++i) {
        int b = b0 + ty * 4 + i;
#pragma unroll
        for (int j = 0; j < 4; ++j) {
            int n = n0 + tx * 4 + j;
            float v = acc[i][j];
            if (bias) v += bias[n];
            C[(size_t)b * 1024 + n] = v;
        }
    }
}

__global__ void kb_kernel(const float* __restrict__ hg, const float* __restrict__ Wo1,
                          const float* __restrict__ uv, const float* __restrict__ octx,
                          const float* __restrict__ mbuf, const float* __restrict__ isbuf,
                          float* __restrict__ o)
{
    __shared__ __align__(16) float At[16 * TS];
    __shared__ __align__(16) float Wt[16 * TS];
    float acc[2][4] = {};
    const int b0 = blockIdx.x * 32, n0 = blockIdx.y * 64;
    const int tid = threadIdx.x, tx = tid & 15, ty = tid >> 4;
    const int r = tid >> 2, c0 = (tid & 3) << 2;
    for (int k0 = 0; k0 < 1024; k0 += 16) {
        float4 av = make_float4(0.f, 0.f, 0.f, 0.f);
        if (r < 32) av = *(const float4*)(hg + (size_t)(b0 + r) * 1024 + k0 + c0);
        float4 wv = *(const float4*)(Wo1 + (size_t)(n0 + r) * 1536 + k0 + c0);
        __syncthreads();
        At[(c0+0)*TS + r] = av.x; At[(c0+1)*TS + r] = av.y;
        At[(c0+2)*TS + r] = av.z; At[(c0+3)*TS + r] = av.w;
        Wt[(c0+0)*TS + r] = wv.x; Wt[(c0+1)*TS + r] = wv.y;
        Wt[(c0+2)*TS + r] = wv.z; Wt[(c0+3)*TS + r] = wv.w;
        __syncthreads();
#pragma unroll
        for (int kk = 0; kk < 16; ++kk) {
            float2 a = *(const float2*)(At + kk*TS + ty*2);
            float4 w = *(const float4*)(Wt + kk*TS + tx*4);
            acc[0][0] += a.x*w.x; acc[0][1] += a.x*w.y; acc[0][2] += a.x*w.z; acc[0][3] += a.x*w.w;
            acc[1][0] += a.y*w.x; acc[1][1] += a.y*w.y; acc[1][2] += a.y*w.z; acc[1][3] += a.y*w.w;
        }
    }
#pragma unroll
    for (int i = 0; i < 2; ++i) {
        int b = b0 + ty * 2 + i;
        float m = mbuf[b], is = isbuf[b];
#pragma unroll
        for (int j = 0; j < 4; ++j) {
            int n = n0 + tx * 4 + j;
            float v = (acc[i][j] - m * uv[n]) * is + uv[1024 + n] + octx[(size_t)b * 1024 + n];
            o[(size_t)b * 1024 + n] = fmaxf(v, 0.f);
        }
    }
}

__global__ void gru_ln_kernel(const float* __restrict__ g6,
                              const float* __restrict__ b_ih, const float* __restrict__ b_hh,
                              float* __restrict__ hBase, const float* __restrict__ ln_g,
                              float* __restrict__ hg, float* __restrict__ mbuf,
                              float* __restrict__ isbuf, int t)
{
    __shared__ float rs[256], rq[256];
    int b = blockIdx.x, tid = threadIdx.x;
    const float* hc = hBase + (size_t)(t & 1) * SZ + (size_t)b * 1024;
    float* hnx = hBase + (size_t)((t + 1) & 1) * SZ + (size_t)b * 1024;
    float s = 0.f, q = 0.f;
#pragma unroll
    for (int jj = 0; jj < 4; ++jj) {
        int j = jj * 256 + tid;
        size_t base = (size_t)b * 1024 + j;
        float xr = g6[0 * (size_t)SZ + base] + b_ih[j];
        float xz = g6[1 * (size_t)SZ + base] + b_ih[1024 + j];
        float xn = g6[2 * (size_t)SZ + base] + b_ih[2048 + j];
        float hr = g6[3 * (size_t)SZ + base] + b_hh[j];
        float hz = g6[4 * (size_t)SZ + base] + b_hh[1024 + j];
        float hn = g6[5 * (size_t)SZ + base] + b_hh[2048 + j];
        float r = 1.f / (1.f + expf(-(xr + hr)));
        float z = 1.f / (1.f + expf(-(xz + hz)));
        float nn = tanhf(xn + r * hn);
        float ho = hc[j];
        float hv = (1.f - z) * nn + z * ho;
        hnx[j] = hv;
        hg[base] = hv * ln_g[j];
        s += hv; q += hv * hv;
    }
    rs[tid] = s; rq[tid] = q;
    __syncthreads();
    for (int st = 128; st; st >>= 1) {
        if (tid < st) { rs[tid] += rs[tid + st]; rq[tid] += rq[tid + st]; }
        __syncthreads();
    }
    if (tid == 0) {
        float m = rs[0] * (1.f / 1024.f);
        float var = rq[0] * (1.f / 1024.f) - m * m;
        mbuf[b] = m;
        isbuf[b] = rsqrtf(var + 1e-5f);
    }
}

__global__ void kc_kernel(const float* __restrict__ o, const float* __restrict__ Wo2t,
                          const float* __restrict__ b_o2, const float* __restrict__ cinBase,
                          const float* __restrict__ bpart, float* __restrict__ x,
                          int* __restrict__ prev, float* __restrict__ out, int t)
{
    __shared__ __align__(16) float os[1024];
    __shared__ float red[4][64];
    __shared__ int sidx;
    int b = blockIdx.x, tid = threadIdx.x;
    const float* orow = o + (size_t)b * 1024;
    *(float4*)&os[tid * 4] = *(const float4*)&orow[tid * 4];
    __syncthreads();
    int n = tid & 63, seg = tid >> 6;
    float p = 0.f;
    int k0 = seg * 256;
#pragma unroll 8
    for (int k = 0; k < 256; ++k) p += os[k0 + k] * Wo2t[(size_t)(k0 + k) * 64 + n];
    red[seg][n] = p;
    __syncthreads();
    if (tid < 64) {
        float lg = red[0][tid] + red[1][tid] + red[2][tid] + red[3][tid] + b_o2[tid];
        out[((size_t)b * TT + t) * 64 + tid] = lg;
        float v = lg; int idx = tid;
        for (int off = 32; off; off >>= 1) {
            float ov = __shfl_xor(v, off);
            int oi = __shfl_xor(idx, off);
            if (ov > v || (ov == v && oi < idx)) { v = ov; idx = oi; }
        }
        if (tid == 0) { prev[b] = idx; sidx = idx; }
    }
    __syncthreads();
    if (t + 1 < TT) {
        int pb = sidx;
        const float* cn = cinBase + (size_t)((t + 1) & 1) * SZ + (size_t)b * 1024;
        const float* bp = bpart + (size_t)pb * 1024;
#pragma unroll
        for (int jj = 0; jj < 4; ++jj) {
            int j = jj * 256 + tid;
            x[(size_t)b * 1024 + j] = fmaxf(cn[j] + bp[j], 0.f);
        }
    }
}

__global__ void copy_gb_kernel(const float* g, const float* bb, float* gb)
{
    int idx = blockIdx.x * 256 + threadIdx.x;
    if (idx < 1024) gb[idx] = g[idx];
    else            gb[idx] = bb[idx - 1024];
}

// ---------------------------------------------------------------------------

extern "C" void kernel_launch(void* const* d_in, const int* in_sizes, int n_in,
                              void* d_out, int out_size, void* d_ws, size_t ws_size,
                              hipStream_t stream)
{
    const float* ctx    = (const float*)d_in[0];
    const int*   bh     = (const int*)d_in[1];
    const float* be     = (const float*)d_in[2];
    const float* W_in   = (const float*)d_in[3];
    const float* b_in   = (const float*)d_in[4];
    const float* W_init = (const float*)d_in[5];
    const float* b_init = (const float*)d_in[6];
    const float* W_ih   = (const float*)d_in[7];
    const float* b_ih   = (const float*)d_in[8];
    const float* W_hh   = (const float*)d_in[9];
    const float* b_hh   = (const float*)d_in[10];
    const float* ln_g   = (const float*)d_in[11];
    const float* ln_b   = (const float*)d_in[12];
    const float* W_o1   = (const float*)d_in[13];
    const float* b_o1   = (const float*)d_in[14];
    const float* W_o2   = (const float*)d_in[15];
    const float* b_o2   = (const float*)d_in[16];
    float* out = (float*)d_out;
    float* ws  = (float*)d_ws;

    const bool mfma_path = (ws_size >= 45700000ull);

    if (mfma_path) {
        // ---- round-12 layout (floats) ----
        float* hbuf  = ws;                  // 256x1024 fp32, in-place h
        float* cin   = ws + 262144;
        float* octx  = ws + 524288;
        float* g6    = ws + 786432;         // 6 slots; 0..3 reused as kb partials
        float* A0    = g6;                  // setup-only alias
        float* bpart = ws + 2359296;        // 64x1024
        float* uvv   = ws + 2424832;        // 2x1024
        float* Wo2t  = ws + 2428928;        // 1024x64
        float* mbuf  = ws + 2494464;
        float* isbuf = ws + 2494720;
        int*   prev  = (int*)(ws + 2494976);
        unsigned short* bf = (unsigned short*)(ws + 2495232);
        unsigned short* wih_hi   = bf;                  // [3072x1024] row-major
        unsigned short* wih_loP  = bf + 3145728;        // packed frags
        unsigned short* whh_hi   = bf + 6291456;
        unsigned short* whh_loP  = bf + 9437184;
        unsigned short* wo1k_hi  = bf + 12582912;       // [1024x1024], ln_g-folded
        unsigned short* wo1k_loP = bf + 13631488;       // packed frags
        unsigned short* wo1c_hi  = bf + 14680064;       // [1024x512] row-major
        unsigned short* wo1c_lo  = bf + 15204352;
        unsigned short* wcin_hi  = bf + 15728640;       // [1024x512] row-major
        unsigned short* wcin_lo  = bf + 16252928;
        unsigned short* xh       = bf + 16777216;
        unsigned short* xl       = bf + 17039360;
        unsigned short* hh       = bf + 17301504;
        unsigned short* hl       = bf + 17563648;
        // end: 2495232*4 + 17825792*2 = 45,632,512 B

        // ---- setup ----
        pre0_kernel<<<256, 512, 0, stream>>>(ctx, bh, be, A0, prev);
        wo2t_kernel<<<256, 256, 0, stream>>>(W_o2, Wo2t);
        uv_kernel<<<8, 256, 0, stream>>>(ln_g, ln_b, W_o1, uvv);
        gemm64_kernel<<<dim3(4, 16), 256, 0, stream>>>(A0, 1024, 256, W_init, 1024, 1024,
                                                       b_init, hbuf, 1024, 1);
        gemm64_kernel<<<dim3(1, 16), 256, 0, stream>>>(be, 512, 64, W_in + 512, 1024, 512,
                                                       nullptr, bpart, 1024, 0);
        gemm64_kernel<<<dim3(4, 16), 256, 0, stream>>>(ctx, LDA_CTX, 256, W_in, 1024, 512,
                                                       b_in, cin, 1024, 0);
        xbuild0s_kernel<<<256, 256, 0, stream>>>(cin, bpart, prev, xh, xl);
        // weight preprocessing
        whi_kernel<<<12288, 256, 0, stream>>>(W_ih, 1024, 0, 3072, 1024, nullptr, wih_hi);
        packlo_kernel<<<12288, 256, 0, stream>>>(W_ih, 1024, 0, 3072, 1024, nullptr, wih_loP);
        whi_kernel<<<12288, 256, 0, stream>>>(W_hh, 1024, 0, 3072, 1024, nullptr, whh_hi);
        packlo_kernel<<<12288, 256, 0, stream>>>(W_hh, 1024, 0, 3072, 1024, nullptr, whh_loP);
        whi_kernel<<<4096, 256, 0, stream>>>(W_o1, 1536, 0, 1024, 1024, ln_g, wo1k_hi);
        packlo_kernel<<<4096, 256, 0, stream>>>(W_o1, 1536, 0, 1024, 1024, ln_g, wo1k_loP);
        wsplit_kernel<<<2048, 256, 0, stream>>>(W_o1, 1536, 1024, 1024, 512, nullptr, wo1c_hi, wo1c_lo);
        wsplit_kernel<<<2048, 256, 0, stream>>>(W_in, 1024, 0, 1024, 512, nullptr, wcin_hi, wcin_lo);
        // h0 split
        wsplit_kernel<<<1024, 256, 0, stream>>>(hbuf, 1024, 0, 256, 1024, nullptr, hh, hl);

        // ---- recurrence: 4 launches/step (proven skeleton) ----
        for (int t = 0; t < TT; ++t) {
            gates12_kernel<<<256, 256, 0, stream>>>(
                xh, xl, hh, hl, ctx,
                wih_hi, wih_loP, whh_hi, whh_loP, wcin_hi, wcin_lo, wo1c_hi, wo1c_lo,
                b_in, b_o1, g6, cin, octx, t);
            gru_ln6_kernel<<<256, 256, 0, stream>>>(g6, b_ih, b_hh, hbuf,
                                                    hh, hl, mbuf, isbuf);
            kb12_kernel<<<128, 256, 0, stream>>>(hh, hl, wo1k_hi, wo1k_loP, g6);
            kc12_kernel<<<64, 256, 0, stream>>>(g6, Wo2t, b_o2, uvv, octx, mbuf, isbuf,
                                                cin, bpart, xh, xl, prev, out, t);
        }
    } else {
        // ---- fallback: round-1 fp32 path ----
        float* A0    = ws;
        float* hbuf  = ws + 262144;
        float* hg    = ws + 786432;
        float* x     = ws + 1048576;
        float* cin   = ws + 1310720;
        float* octx  = ws + 1835008;
        float* g6    = ws + 2097152;
        float* obuf  = ws + 3670016;
        float* bpart = ws + 3932160;
        float* uvv   = ws + 3997696;
        float* gb    = ws + 3999744;
        float* Wo2t  = ws + 4001792;
        float* mbuf  = ws + 4067328;
        float* isbuf = ws + 4067584;
        int*   prev  = (int*)(ws + 4067840);

        pre0_kernel<<<256, 512, 0, stream>>>(ctx, bh, be, A0, prev);
        copy_gb_kernel<<<8, 256, 0, stream>>>(ln_g, ln_b, gb);
        wo2t_kernel<<<256, 256, 0, stream>>>(W_o2, Wo2t);
        gemm64_kernel<<<dim3(4, 16), 256, 0, stream>>>(A0, 1024, 256, W_init, 1024, 1024,
                                                       b_init, hbuf, 1024, 1);
        gemm64_kernel<<<dim3(1, 16), 256, 0, stream>>>(be, 512, 64, W_in + 512, 1024, 512,
                                                       nullptr, bpart, 1024, 0);
        gemm64_kernel<<<dim3(1, 16), 256, 0, stream>>>(gb, 1024, 2, W_o1, 1536, 1024,
                                                       nullptr, uvv, 1024, 0);
        gemm64_kernel<<<dim3(4, 16), 256, 0, stream>>>(ctx, LDA_CTX, 256, W_in, 1024, 512,
                                                       b_in, cin, 1024, 0);
        xbuild0_kernel<<<256, 256, 0, stream>>>(cin, bpart, prev, x);

        for (int t = 0; t < TT; ++t) {
            step_gemms_kernel<<<dim3(4, 16, 8), 256, 0, stream>>>(
                x, hbuf, ctx, W_ih, W_hh, W_in, W_o1, b_in, b_o1, g6, cin, octx, t);
            gru_ln_kernel<<<256, 256, 0, stream>>>(g6, b_ih, b_hh, hbuf, ln_g, hg,
                                                   mbuf, isbuf, t);
            kb_kernel<<<dim3(8, 16), 256, 0, stream>>>(hg, W_o1, uvv, octx, mbuf, isbuf, obuf);
            kc_kernel<<<256, 256, 0, stream>>>(obuf, Wo2t, b_o2, cin, bpart, x, prev, out, t);
        }
    }
}

// Round 13
// 6590.781 us; speedup vs baseline: 3.8540x; 1.1128x over previous
//
#include <hip/hip_runtime.h>
#include <hip/hip_bf16.h>

// ---------------------------------------------------------------------------
// AutoregressiveBeamDecoder: B=256, T=128, D=512, H=1024, NB=64, HH=8
// Round 13: round-12 skeleton (4 launches/step, 7.33 ms) with B FULLY packed
// (hi AND lo as MFMA fragments in global); LDS holds only the A tile.
// Per K-iter per block: LDS 48KB -> 24KB. MFMA order unchanged (bit-exact).
// gru vectorized to float4/ushort4.
// C = Ahi@Bhi + Ahi@Blo + Alo@Bhi (3x mfma_f32_16x16x32_bf16, fp32 accum)
// ---------------------------------------------------------------------------

#define TS 68          // fp32 LDS row stride (fallback path only)
#define LDPA 40        // bf16 LDS row stride (shorts): 80 B
constexpr int SZ = 262144;     // 256*1024
constexpr int TT = 128;        // T
constexpr int LDA_CTX = 65536; // T*D

typedef __attribute__((ext_vector_type(8))) short short8_t;
typedef __attribute__((ext_vector_type(4))) float f32x4;

// ---------------- bf16 split helpers (bit-level, RNE) ----------------------

__device__ __forceinline__ unsigned short f2bf_rne(float v) {
    unsigned u = __float_as_uint(v);
    unsigned r = u + 0x7fffu + ((u >> 16) & 1u);
    return (unsigned short)(r >> 16);
}
__device__ __forceinline__ float bfbits2f(unsigned short h) {
    return __uint_as_float(((unsigned)h) << 16);
}
__device__ __forceinline__ void split2(float v, unsigned short& h, unsigned short& l) {
    h = f2bf_rne(v);
    l = f2bf_rne(v - bfbits2f(h));
}
__device__ __forceinline__ void splitA8(const float4& v0, const float4& v1,
                                        short8_t& hi, short8_t& lo) {
    unsigned short h[8], l[8];
    split2(v0.x, h[0], l[0]); split2(v0.y, h[1], l[1]);
    split2(v0.z, h[2], l[2]); split2(v0.w, h[3], l[3]);
    split2(v1.x, h[4], l[4]); split2(v1.y, h[5], l[5]);
    split2(v1.z, h[6], l[6]); split2(v1.w, h[7], l[7]);
    hi = short8_t{(short)h[0],(short)h[1],(short)h[2],(short)h[3],
                  (short)h[4],(short)h[5],(short)h[6],(short)h[7]};
    lo = short8_t{(short)l[0],(short)l[1],(short)l[2],(short)l[3],
                  (short)l[4],(short)l[5],(short)l[6],(short)l[7]};
}

// ---------------- core13b: A bf16 presplit in LDS, B hi+lo packed global ---
// block 64(M) x 128(N), 256 thr = 4 waves; wave (wr=wid>>1, wc=wid&1) owns
// 32x64 = 2 A-frags x 4 B-frags. BK=32, double-buffered A, 1 barrier/iter.
// sm shorts/buf: Ah[64*40]=2560 | Al 2560  -> 5120/buf, x2 = 20KB.
// B packed frags: frag nf at BP + (nf*nKs + ks)*512 + lane*8.

__device__ __forceinline__ void core13b(
    const unsigned short* __restrict__ Ah, const unsigned short* __restrict__ Al,
    int lda, int b0,
    const unsigned short* __restrict__ BhP, const unsigned short* __restrict__ BlP,
    int nKs, int ksbase, int nfb,
    int nIter, unsigned short* sm, f32x4 acc[2][4])
{
    const int tid = threadIdx.x, lane = tid & 63, wid = tid >> 6;
    const int wr = wid >> 1, wc = wid & 1;
    const int l15 = lane & 15, kg = (lane >> 4) * 8;
    const int arow = tid >> 2, acol = (tid & 3) * 8;   // A: 4 thr/row

    const int ALO = 2560, BUF = 5120;

    const unsigned short* gAh = Ah + (size_t)(b0 + arow) * lda + ksbase * 32 + acol;
    const unsigned short* gAl = Al + (size_t)(b0 + arow) * lda + ksbase * 32 + acol;
    const unsigned short* pBh[4];
    const unsigned short* pBl[4];
#pragma unroll
    for (int ni = 0; ni < 4; ++ni) {
        pBh[ni] = BhP + ((size_t)(nfb + ni) * nKs + ksbase) * 512 + lane * 8;
        pBl[ni] = BlP + ((size_t)(nfb + ni) * nKs + ksbase) * 512 + lane * 8;
    }

    short8_t cBh[4], cBl[4], nBh[4], nBl[4];
    {
        short8_t a_h = *(const short8_t*)gAh;
        short8_t a_l = *(const short8_t*)gAl;
        *(short8_t*)&sm[arow * LDPA + acol]       = a_h;
        *(short8_t*)&sm[ALO + arow * LDPA + acol] = a_l;
#pragma unroll
        for (int ni = 0; ni < 4; ++ni) {
            cBh[ni] = *(const short8_t*)pBh[ni];
            cBl[ni] = *(const short8_t*)pBl[ni];
        }
    }
    __syncthreads();

    int cur = 0;
    const int aro = (wr * 32 + l15) * LDPA + kg;
    for (int i = 0; i < nIter; ++i) {
        short8_t a_h, a_l;
        if (i + 1 < nIter) {               // prefetch next tile (under compute)
            const int ko = (i + 1) * 32;
            a_h = *(const short8_t*)(gAh + ko);
            a_l = *(const short8_t*)(gAl + ko);
            const size_t fo = (size_t)(i + 1) * 512;
#pragma unroll
            for (int ni = 0; ni < 4; ++ni) {
                nBh[ni] = *(const short8_t*)(pBh[ni] + fo);
                nBl[ni] = *(const short8_t*)(pBl[ni] + fo);
            }
        }
        const unsigned short* S = sm + cur * BUF;
        short8_t afh[2], afl[2];
#pragma unroll
        for (int mi = 0; mi < 2; ++mi) {
            afh[mi] = *(const short8_t*)&S[aro + mi * 16 * LDPA];
            afl[mi] = *(const short8_t*)&S[ALO + aro + mi * 16 * LDPA];
        }
#pragma unroll
        for (int ni = 0; ni < 4; ++ni) {
#pragma unroll
            for (int mi = 0; mi < 2; ++mi) {
                acc[mi][ni] = __builtin_amdgcn_mfma_f32_16x16x32_bf16(afh[mi], cBh[ni], acc[mi][ni], 0, 0, 0);
                acc[mi][ni] = __builtin_amdgcn_mfma_f32_16x16x32_bf16(afh[mi], cBl[ni], acc[mi][ni], 0, 0, 0);
                acc[mi][ni] = __builtin_amdgcn_mfma_f32_16x16x32_bf16(afl[mi], cBh[ni], acc[mi][ni], 0, 0, 0);
            }
        }
        if (i + 1 < nIter) {
            unsigned short* N_ = sm + (cur ^ 1) * BUF;
            *(short8_t*)&N_[arow * LDPA + acol]       = a_h;
            *(short8_t*)&N_[ALO + arow * LDPA + acol] = a_l;
        }
        __syncthreads();
        cur ^= 1;
#pragma unroll
        for (int ni = 0; ni < 4; ++ni) { cBh[ni] = nBh[ni]; cBl[ni] = nBl[ni]; }
    }
}

// ---------------- core9: A fp32 (in-register split), B hi/lo in LDS --------
// Used only for the two ctx GEMMs (z=6,7), K=512. Round-10 verified.

__device__ __forceinline__ void mfma_core9(
    const float* __restrict__ A, int lda, int b0,
    const unsigned short* __restrict__ Bh, const unsigned short* __restrict__ Bl,
    int ldb, int n0, int k0base, int nIter,
    unsigned short* sm, f32x4 acc[2][4])
{
    const int tid = threadIdx.x, lane = tid & 63, wid = tid >> 6;
    const int wr = wid >> 1, wc = wid & 1;
    const int l15 = lane & 15, kg = (lane >> 4) * 8;
    const int arow = tid >> 2, acol = (tid & 3) * 8;
    const int brow = tid >> 1, bcol = (tid & 1) * 16;

    const int AOFF = 2560, BHOFF = 5120, BLOFF = 10240, BUF = 15360;

    const float* gA = A + (size_t)(b0 + arow) * lda + k0base + acol;
    const unsigned short* gBh = Bh + (size_t)(n0 + brow) * ldb + k0base + bcol;
    const unsigned short* gBl = Bl + (size_t)(n0 + brow) * ldb + k0base + bcol;

    {
        float4 a0 = *(const float4*)gA;
        float4 a1 = *(const float4*)(gA + 4);
        short8_t ah, al;
        splitA8(a0, a1, ah, al);
        short8_t bh0 = *(const short8_t*)gBh;
        short8_t bh1 = *(const short8_t*)(gBh + 8);
        short8_t bl0 = *(const short8_t*)gBl;
        short8_t bl1 = *(const short8_t*)(gBl + 8);
        *(short8_t*)&sm[arow * LDPA + acol]              = ah;
        *(short8_t*)&sm[AOFF + arow * LDPA + acol]       = al;
        *(short8_t*)&sm[BHOFF + brow * LDPA + bcol]      = bh0;
        *(short8_t*)&sm[BHOFF + brow * LDPA + bcol + 8]  = bh1;
        *(short8_t*)&sm[BLOFF + brow * LDPA + bcol]      = bl0;
        *(short8_t*)&sm[BLOFF + brow * LDPA + bcol + 8]  = bl1;
    }
    __syncthreads();

    int cur = 0;
    const int aro = (wr * 32 + l15) * LDPA + kg;
    for (int i = 0; i < nIter; ++i) {
        float4 a0, a1;
        short8_t bh0, bh1, bl0, bl1;
        if (i + 1 < nIter) {
            const int ko = (i + 1) * 32;
            a0 = *(const float4*)(gA + ko);
            a1 = *(const float4*)(gA + ko + 4);
            bh0 = *(const short8_t*)(gBh + ko);
            bh1 = *(const short8_t*)(gBh + ko + 8);
            bl0 = *(const short8_t*)(gBl + ko);
            bl1 = *(const short8_t*)(gBl + ko + 8);
        }
        const unsigned short* S = sm + cur * BUF;
        short8_t afh[2], afl[2];
#pragma unroll
        for (int mi = 0; mi < 2; ++mi) {
            afh[mi] = *(const short8_t*)&S[aro + mi * 16 * LDPA];
            afl[mi] = *(const short8_t*)&S[AOFF + aro + mi * 16 * LDPA];
        }
#pragma unroll
        for (int ni = 0; ni < 4; ++ni) {
            const int bro = (wc * 64 + ni * 16 + l15) * LDPA + kg;
            short8_t b_h = *(const short8_t*)&S[BHOFF + bro];
            short8_t b_l = *(const short8_t*)&S[BLOFF + bro];
#pragma unroll
            for (int mi = 0; mi < 2; ++mi) {
                acc[mi][ni] = __builtin_amdgcn_mfma_f32_16x16x32_bf16(afh[mi], b_h, acc[mi][ni], 0, 0, 0);
                acc[mi][ni] = __builtin_amdgcn_mfma_f32_16x16x32_bf16(afh[mi], b_l, acc[mi][ni], 0, 0, 0);
                acc[mi][ni] = __builtin_amdgcn_mfma_f32_16x16x32_bf16(afl[mi], b_h, acc[mi][ni], 0, 0, 0);
            }
        }
        if (i + 1 < nIter) {
            short8_t ah, al;
            splitA8(a0, a1, ah, al);
            unsigned short* N_ = sm + (cur ^ 1) * BUF;
            *(short8_t*)&N_[arow * LDPA + acol]             = ah;
            *(short8_t*)&N_[AOFF + arow * LDPA + acol]      = al;
            *(short8_t*)&N_[BHOFF + brow * LDPA + bcol]     = bh0;
            *(short8_t*)&N_[BHOFF + brow * LDPA + bcol + 8] = bh1;
            *(short8_t*)&N_[BLOFF + brow * LDPA + bcol]     = bl0;
            *(short8_t*)&N_[BLOFF + brow * LDPA + bcol + 8] = bl1;
        }
        __syncthreads();
        cur ^= 1;
    }
}

// ---------------- fp32 tiled GEMM core (setup + fallback) ------------------

__device__ __forceinline__ void gemm_tile64(
    const float* __restrict__ A, int lda, int Mlim, int b0,
    const float* __restrict__ W, int ldw, int n0, int K,
    float* At, float* Wt, float acc[4][4])
{
    const int tid = threadIdx.x;
    const int tx = tid & 15, ty = tid >> 4;
    const int r = tid >> 2, c0 = (tid & 3) << 2;
    for (int k0 = 0; k0 < K; k0 += 16) {
        float4 av = make_float4(0.f, 0.f, 0.f, 0.f);
        if (b0 + r < Mlim)
            av = *(const float4*)(A + (size_t)(b0 + r) * lda + k0 + c0);
        float4 wv = *(const float4*)(W + (size_t)(n0 + r) * ldw + k0 + c0);
        __syncthreads();
        At[(c0+0)*TS + r] = av.x; At[(c0+1)*TS + r] = av.y;
        At[(c0+2)*TS + r] = av.z; At[(c0+3)*TS + r] = av.w;
        Wt[(c0+0)*TS + r] = wv.x; Wt[(c0+1)*TS + r] = wv.y;
        Wt[(c0+2)*TS + r] = wv.z; Wt[(c0+3)*TS + r] = wv.w;
        __syncthreads();
#pragma unroll
        for (int kk = 0; kk < 16; ++kk) {
            float4 a = *(const float4*)(At + kk*TS + ty*4);
            float4 w = *(const float4*)(Wt + kk*TS + tx*4);
            acc[0][0] += a.x*w.x; acc[0][1] += a.x*w.y; acc[0][2] += a.x*w.z; acc[0][3] += a.x*w.w;
            acc[1][0] += a.y*w.x; acc[1][1] += a.y*w.y; acc[1][2] += a.y*w.z; acc[1][3] += a.y*w.w;
            acc[2][0] += a.z*w.x; acc[2][1] += a.z*w.y; acc[2][2] += a.z*w.z; acc[2][3] += a.z*w.w;
            acc[3][0] += a.w*w.x; acc[3][1] += a.w*w.y; acc[3][2] += a.w*w.z; acc[3][3] += a.w*w.w;
        }
    }
}

// -------------------- setup kernels ----------------------------------------

__global__ void pre0_kernel(const float* __restrict__ ctx, const int* __restrict__ bh,
                            const float* __restrict__ be, float* __restrict__ A0,
                            int* __restrict__ prev)
{
    int b = blockIdx.x, tid = threadIdx.x; // blockDim 512
    float s = 0.f;
    for (int t = 0; t < TT; ++t) s += ctx[(size_t)b * LDA_CTX + t * 512 + tid];
    A0[b * 1024 + tid] = s * (1.f / 128.f);
    float s2 = 0.f;
    for (int i = 0; i < 8; ++i) s2 += be[bh[b * 8 + i] * 512 + tid];
    A0[b * 1024 + 512 + tid] = s2 * 0.125f;
    if (tid == 0) prev[b] = bh[b * 8 + 7];
}

__global__ void wo2t_kernel(const float* __restrict__ W_o2, float* __restrict__ Wo2t)
{
    int idx = blockIdx.x * 256 + threadIdx.x;
    int k = idx >> 6, n = idx & 63;
    Wo2t[idx] = W_o2[n * 1024 + k];
}

__global__ void uv_kernel(const float* __restrict__ ln_g, const float* __restrict__ ln_b,
                          const float* __restrict__ W_o1, float* __restrict__ uvv)
{
    int idx = blockIdx.x * 256 + threadIdx.x; // 8 blocks -> 2048
    int which = idx >> 10, j = idx & 1023;
    const float* vec = which ? ln_b : ln_g;
    float s = 0.f;
    for (int k = 0; k < 1024; ++k) s += vec[k] * W_o1[(size_t)j * 1536 + k];
    uvv[which * 1024 + j] = s;
}

// hi packed in MFMA fragment order
__global__ void packhi_kernel(const float* __restrict__ src, int ld, int col0,
                              int N, int K, const float* __restrict__ scale,
                              unsigned short* __restrict__ hi)
{
    int idx = blockIdx.x * 256 + threadIdx.x;
    if (idx >= N * K) return;
    int j = idx & 7;
    int lane = (idx >> 3) & 63;
    int fs = idx >> 9;
    int nKs = K >> 5;
    int nf = fs / nKs, ks = fs - nf * nKs;
    int n = nf * 16 + (lane & 15);
    int k = ks * 32 + (lane >> 4) * 8 + j;
    float v = src[(size_t)n * ld + col0 + k];
    if (scale) v *= scale[k];
    hi[idx] = f2bf_rne(v);
}

// lo packed in MFMA fragment order
__global__ void packlo_kernel(const float* __restrict__ src, int ld, int col0,
                              int N, int K, const float* __restrict__ scale,
                              unsigned short* __restrict__ lo)
{
    int idx = blockIdx.x * 256 + threadIdx.x;
    if (idx >= N * K) return;
    int j = idx & 7;
    int lane = (idx >> 3) & 63;
    int fs = idx >> 9;
    int nKs = K >> 5;
    int nf = fs / nKs, ks = fs - nf * nKs;
    int n = nf * 16 + (lane & 15);
    int k = ks * 32 + (lane >> 4) * 8 + j;
    float v = src[(size_t)n * ld + col0 + k];
    if (scale) v *= scale[k];
    unsigned short h, l;
    split2(v, h, l);
    lo[idx] = l;
}

// row-major hi + lo
__global__ void wsplit_kernel(const float* __restrict__ src, int src_ld, int col0,
                              int N, int K, const float* __restrict__ scale,
                              unsigned short* __restrict__ hi,
                              unsigned short* __restrict__ lo)
{
    int idx = blockIdx.x * 256 + threadIdx.x;
    if (idx >= N * K) return;
    int n = idx / K, k = idx - n * K;
    float v = src[(size_t)n * src_ld + col0 + k];
    if (scale) v *= scale[k];
    unsigned short h, l;
    split2(v, h, l);
    hi[idx] = h; lo[idx] = l;
}

__global__ void gemm64_kernel(const float* __restrict__ A, int lda, int M,
                              const float* __restrict__ W, int ldw, int K,
                              const float* __restrict__ bias,
                              float* __restrict__ C, int ldc, int act)
{
    __shared__ __align__(16) float At[16 * TS];
    __shared__ __align__(16) float Wt[16 * TS];
    float acc[4][4] = {};
    int b0 = blockIdx.x * 64, n0 = blockIdx.y * 64;
    gemm_tile64(A, lda, M, b0, W, ldw, n0, K, At, Wt, acc);
    int tx = threadIdx.x & 15, ty = threadIdx.x >> 4;
#pragma unroll
    for (int i = 0; i < 4; ++i) {
        int b = b0 + ty * 4 + i;
        if (b >= M) continue;
#pragma unroll
        for (int j = 0; j < 4; ++j) {
            int n = n0 + tx * 4 + j;
            float v = acc[i][j] + (bias ? bias[n] : 0.f);
            if (act == 1) v = tanhf(v);
            C[(size_t)b * ldc + n] = v;
        }
    }
}

__global__ void xbuild0s_kernel(const float* __restrict__ cin0, const float* __restrict__ bpart,
                                const int* __restrict__ prev,
                                unsigned short* __restrict__ xh, unsigned short* __restrict__ xl)
{
    int b = blockIdx.x, tid = threadIdx.x;
    int pb = prev[b];
#pragma unroll
    for (int jj = 0; jj < 4; ++jj) {
        int j = jj * 256 + tid;
        float v = fmaxf(cin0[(size_t)b * 1024 + j] + bpart[(size_t)pb * 1024 + j], 0.f);
        unsigned short h, l;
        split2(v, h, l);
        xh[(size_t)b * 1024 + j] = h;
        xl[(size_t)b * 1024 + j] = l;
    }
}

__global__ void xbuild0_kernel(const float* __restrict__ cin0, const float* __restrict__ bpart,
                               const int* __restrict__ prev, float* __restrict__ x)
{
    int b = blockIdx.x, tid = threadIdx.x;
    int pb = prev[b];
#pragma unroll
    for (int jj = 0; jj < 4; ++jj) {
        int j = jj * 256 + tid;
        x[(size_t)b * 1024 + j] = fmaxf(cin0[(size_t)b * 1024 + j] + bpart[(size_t)pb * 1024 + j], 0.f);
    }
}

// -------------------- per-step kernels (round 13) --------------------------

// Fused 8-way GEMM; grid 256: bid = tile*8 + z (XCD class = z).
__global__ __launch_bounds__(256) void gates13_kernel(
    const unsigned short* __restrict__ xh, const unsigned short* __restrict__ xl,
    const unsigned short* __restrict__ hh, const unsigned short* __restrict__ hl,
    const float* __restrict__ ctx,
    const unsigned short* __restrict__ wih_hiP, const unsigned short* __restrict__ wih_loP,
    const unsigned short* __restrict__ whh_hiP, const unsigned short* __restrict__ whh_loP,
    const unsigned short* __restrict__ wcin_hi, const unsigned short* __restrict__ wcin_lo,
    const unsigned short* __restrict__ wo1c_hi, const unsigned short* __restrict__ wo1c_lo,
    const float* __restrict__ b_in, const float* __restrict__ b_o1,
    float* __restrict__ g6, float* __restrict__ cin, float* __restrict__ octx,
    int t)
{
    const int bid = blockIdx.x;
    const int z = bid & 7;
    const int tile = bid >> 3;
    const int tm = tile & 3, tn = tile >> 2;
    if (z == 6 && t + 1 >= TT) return;
    const int b0 = tm * 64, n0 = tn * 128;

    __shared__ __align__(16) unsigned short sm[2 * 15360];
    f32x4 acc[2][4] = {};
    const float* bias = nullptr;
    float* C;
    const int wid = threadIdx.x >> 6, wc = wid & 1;

    if (z < 6) {
        int g = z % 3, s = z / 3;
        const unsigned short* Ah = s ? hh : xh;
        const unsigned short* Al = s ? hl : xl;
        const unsigned short* BhP = s ? whh_hiP : wih_hiP;
        const unsigned short* BlP = s ? whh_loP : wih_loP;
        const int nfb = g * 64 + (n0 >> 4) + wc * 4;
        C = g6 + (size_t)z * SZ;
        core13b(Ah, Al, 1024, b0, BhP, BlP, 32, 0, nfb, 32, sm, acc);
    } else if (z == 6) {
        const float* A = ctx + (size_t)(t + 1) * 512;
        bias = b_in; C = cin;
        mfma_core9(A, LDA_CTX, b0, wcin_hi, wcin_lo, 512, n0, 0, 16, sm, acc);
    } else {
        const float* A = ctx + (size_t)t * 512;
        bias = b_o1; C = octx;
        mfma_core9(A, LDA_CTX, b0, wo1c_hi, wo1c_lo, 512, n0, 0, 16, sm, acc);
    }

    const int lane = threadIdx.x & 63;
    const int wr = wid >> 1;
    const int l15 = lane & 15, g4 = (lane >> 4) * 4;
#pragma unroll
    for (int mi = 0; mi < 2; ++mi) {
#pragma unroll
        for (int ni = 0; ni < 4; ++ni) {
            int col = n0 + wc * 64 + ni * 16 + l15;
            float bv = bias ? bias[col] : 0.f;
#pragma unroll
            for (int r = 0; r < 4; ++r) {
                int row = b0 + wr * 32 + mi * 16 + g4 + r;
                C[(size_t)row * 1024 + col] = acc[mi][ni][r] + bv;
            }
        }
    }
}

// o-GEMM raw partials, K-split 4 into g6 slots 0..3; grid 128:
// bid = tm*32 + tn*4 + p
__global__ __launch_bounds__(256) void kb13_kernel(
    const unsigned short* __restrict__ hh, const unsigned short* __restrict__ hl,
    const unsigned short* __restrict__ wo1k_hiP, const unsigned short* __restrict__ wo1k_loP,
    float* __restrict__ g6)
{
    const int bid = blockIdx.x;
    const int tm = bid >> 5, tn = (bid >> 2) & 7, p = bid & 3;
    const int b0 = tm * 64, n0 = tn * 128;
    const int wid = threadIdx.x >> 6, wc = wid & 1;

    __shared__ __align__(16) unsigned short sm[2 * 5120];
    f32x4 acc[2][4] = {};
    core13b(hh, hl, 1024, b0, wo1k_hiP, wo1k_loP, 32, p * 8,
            (n0 >> 4) + wc * 4, 8, sm, acc);

    float* C = g6 + (size_t)p * SZ;
    const int lane = threadIdx.x & 63;
    const int wr = wid >> 1;
    const int l15 = lane & 15, g4 = (lane >> 4) * 4;
#pragma unroll
    for (int mi = 0; mi < 2; ++mi) {
#pragma unroll
        for (int ni = 0; ni < 4; ++ni) {
            int col = n0 + wc * 64 + ni * 16 + l15;
#pragma unroll
            for (int r = 0; r < 4; ++r) {
                int row = b0 + wr * 32 + mi * 16 + g4 + r;
                C[(size_t)row * 1024 + col] = acc[mi][ni][r];
            }
        }
    }
}

// GRU combine + LN stats (vectorized); writes h fp32 in-place + split h
__global__ void gru13_kernel(const float* __restrict__ g6,
                             const float* __restrict__ b_ih, const float* __restrict__ b_hh,
                             float* __restrict__ h,
                             unsigned short* __restrict__ hh, unsigned short* __restrict__ hl,
                             float* __restrict__ mbuf, float* __restrict__ isbuf)
{
    __shared__ float ls[4], lq[4];
    const int b = blockIdx.x, tid = threadIdx.x;
    const int j = tid * 4;
    size_t base = (size_t)b * 1024 + j;
    float4 xr = *(const float4*)(g6 + base);
    float4 xz = *(const float4*)(g6 + (size_t)SZ + base);
    float4 xn = *(const float4*)(g6 + 2 * (size_t)SZ + base);
    float4 hr = *(const float4*)(g6 + 3 * (size_t)SZ + base);
    float4 hz = *(const float4*)(g6 + 4 * (size_t)SZ + base);
    float4 hn = *(const float4*)(g6 + 5 * (size_t)SZ + base);
    float4 ho = *(const float4*)(h + base);
    float4 bi0 = *(const float4*)(b_ih + j);
    float4 bi1 = *(const float4*)(b_ih + 1024 + j);
    float4 bi2 = *(const float4*)(b_ih + 2048 + j);
    float4 bh0 = *(const float4*)(b_hh + j);
    float4 bh1 = *(const float4*)(b_hh + 1024 + j);
    float4 bh2 = *(const float4*)(b_hh + 2048 + j);
    float4 hv;
    {
        float rr = 1.f / (1.f + expf(-((xr.x + bi0.x) + (hr.x + bh0.x))));
        float zz = 1.f / (1.f + expf(-((xz.x + bi1.x) + (hz.x + bh1.x))));
        float nn = tanhf((xn.x + bi2.x) + rr * (hn.x + bh2.x));
        hv.x = (1.f - zz) * nn + zz * ho.x;
    }
    {
        float rr = 1.f / (1.f + expf(-((xr.y + bi0.y) + (hr.y + bh0.y))));
        float zz = 1.f / (1.f + expf(-((xz.y + bi1.y) + (hz.y + bh1.y))));
        float nn = tanhf((xn.y + bi2.y) + rr * (hn.y + bh2.y));
        hv.y = (1.f - zz) * nn + zz * ho.y;
    }
    {
        float rr = 1.f / (1.f + expf(-((xr.z + bi0.z) + (hr.z + bh0.z))));
        float zz = 1.f / (1.f + expf(-((xz.z + bi1.z) + (hz.z + bh1.z))));
        float nn = tanhf((xn.z + bi2.z) + rr * (hn.z + bh2.z));
        hv.z = (1.f - zz) * nn + zz * ho.z;
    }
    {
        float rr = 1.f / (1.f + expf(-((xr.w + bi0.w) + (hr.w + bh0.w))));
        float zz = 1.f / (1.f + expf(-((xz.w + bi1.w) + (hz.w + bh1.w))));
        float nn = tanhf((xn.w + bi2.w) + rr * (hn.w + bh2.w));
        hv.w = (1.f - zz) * nn + zz * ho.w;
    }
    *(float4*)(h + base) = hv;
    ushort4 h4, l4;
    split2(hv.x, h4.x, l4.x); split2(hv.y, h4.y, l4.y);
    split2(hv.z, h4.z, l4.z); split2(hv.w, h4.w, l4.w);
    *(ushort4*)(hh + base) = h4;
    *(ushort4*)(hl + base) = l4;
    float s = hv.x + hv.y + hv.z + hv.w;
    float q = hv.x * hv.x + hv.y * hv.y + hv.z * hv.z + hv.w * hv.w;
    for (int off = 32; off; off >>= 1) {
        s += __shfl_down(s, off);
        q += __shfl_down(q, off);
    }
    const int lane = tid & 63, w = tid >> 6;
    if (lane == 0) { ls[w] = s; lq[w] = q; }
    __syncthreads();
    if (tid == 0) {
        float S = ls[0] + ls[1] + ls[2] + ls[3];
        float Q = lq[0] + lq[1] + lq[2] + lq[3];
        float m = S * (1.f / 1024.f);
        mbuf[b] = m;
        isbuf[b] = rsqrtf(Q * (1.f / 1024.f) - m * m + 1e-5f);
    }
}

// partial-sum + LN epilogue + logits + argmax + x split build
// 64 blocks x 256 thr, 4 rows each
__global__ void kc13_kernel(const float* __restrict__ g6,
                            const float* __restrict__ Wo2t, const float* __restrict__ b_o2,
                            const float* __restrict__ uv, const float* __restrict__ octx,
                            const float* __restrict__ mbuf, const float* __restrict__ isbuf,
                            const float* __restrict__ cin, const float* __restrict__ bpart,
                            unsigned short* __restrict__ xh, unsigned short* __restrict__ xl,
                            int* __restrict__ prev, float* __restrict__ out, int t)
{
    __shared__ __align__(16) float os[4][1024];
    __shared__ float red[4][4][64];
    __shared__ int sidx[4];
    const int b0 = blockIdx.x * 4, tid = threadIdx.x;

#pragma unroll
    for (int i = 0; i < 4; ++i) {
        int f = tid + i * 256;
        int r = f >> 8, c4 = (f & 255) << 2;
        size_t base = (size_t)(b0 + r) * 1024 + c4;
        float4 p0 = *(const float4*)(g6 + base);
        float4 p1 = *(const float4*)(g6 + (size_t)SZ + base);
        float4 p2 = *(const float4*)(g6 + 2 * (size_t)SZ + base);
        float4 p3 = *(const float4*)(g6 + 3 * (size_t)SZ + base);
        float4 oc = *(const float4*)(octx + base);
        float4 u4 = *(const float4*)(uv + c4);
        float4 v4 = *(const float4*)(uv + 1024 + c4);
        float m = mbuf[b0 + r], is = isbuf[b0 + r];
        float4 o4;
        o4.x = fmaxf((p0.x + p1.x + p2.x + p3.x - m * u4.x) * is + v4.x + oc.x, 0.f);
        o4.y = fmaxf((p0.y + p1.y + p2.y + p3.y - m * u4.y) * is + v4.y + oc.y, 0.f);
        o4.z = fmaxf((p0.z + p1.z + p2.z + p3.z - m * u4.z) * is + v4.z + oc.z, 0.f);
        o4.w = fmaxf((p0.w + p1.w + p2.w + p3.w - m * u4.w) * is + v4.w + oc.w, 0.f);
        *(float4*)&os[r][c4] = o4;
    }
    __syncthreads();

    {
        int n = tid & 63, seg = tid >> 6;
        float p0 = 0.f, p1 = 0.f, p2 = 0.f, p3 = 0.f;
        int k0 = seg * 256;
        for (int k = k0; k < k0 + 256; ++k) {
            float w = Wo2t[(size_t)k * 64 + n];
            p0 += os[0][k] * w; p1 += os[1][k] * w;
            p2 += os[2][k] * w; p3 += os[3][k] * w;
        }
        red[0][seg][n] = p0; red[1][seg][n] = p1;
        red[2][seg][n] = p2; red[3][seg][n] = p3;
    }
    __syncthreads();

    {
        int r = tid >> 6, n = tid & 63;
        float lg = red[r][0][n] + red[r][1][n] + red[r][2][n] + red[r][3][n] + b_o2[n];
        out[(size_t)(b0 + r) * (TT * 64) + t * 64 + n] = lg;
        float v = lg; int idx = n;
        for (int off = 32; off; off >>= 1) {
            float ov = __shfl_xor(v, off);
            int oi = __shfl_xor(idx, off);
            if (ov > v || (ov == v && oi < idx)) { v = ov; idx = oi; }
        }
        if (n == 0) { prev[b0 + r] = idx; sidx[r] = idx; }
    }
    __syncthreads();

    if (t + 1 < TT) {
#pragma unroll
        for (int i = 0; i < 16; ++i) {
            int idx = tid + i * 256;       // 0..4095
            int r = idx >> 10, j = idx & 1023;
            float v = fmaxf(cin[(size_t)(b0 + r) * 1024 + j] +
                            bpart[(size_t)sidx[r] * 1024 + j], 0.f);
            unsigned short h, l;
            split2(v, h, l);
            xh[(size_t)(b0 + r) * 1024 + j] = h;
            xl[(size_t)(b0 + r) * 1024 + j] = l;
        }
    }
}

// -------------------- fallback fp32 step kernels (round 1) -----------------

__global__ void step_gemms_kernel(
    const float* __restrict__ x, const float* __restrict__ hBase,
    const float* __restrict__ ctx,
    const float* __restrict__ Wih, const float* __restrict__ Whh,
    const float* __restrict__ Win, const float* __restrict__ Wo1,
    const float* __restrict__ b_in, const float* __restrict__ b_o1,
    float* __restrict__ g6, float* __restrict__ cinBase, float* __restrict__ octx,
    int t)
{
    __shared__ __align__(16) float At[16 * TS];
    __shared__ __align__(16) float Wt[16 * TS];
    float acc[4][4] = {};
    const int z = blockIdx.z, b0 = blockIdx.x * 64, n0 = blockIdx.y * 64;
    const float *A, *W, *bias = nullptr;
    float* C;
    int lda, ldw, K;
    if (z < 6) {
        int g = z % 3, s = z / 3;
        A = s ? (hBase + (size_t)(t & 1) * SZ) : x;
        lda = 1024;
        W = (s ? Whh : Wih) + (size_t)(g * 1024) * 1024;
        ldw = 1024; K = 1024;
        C = g6 + (size_t)z * SZ;
    } else if (z == 6) {
        if (t + 1 >= TT) return;
        A = ctx + (size_t)(t + 1) * 512; lda = LDA_CTX;
        W = Win; ldw = 1024; K = 512; bias = b_in;
        C = cinBase + (size_t)((t + 1) & 1) * SZ;
    } else {
        A = ctx + (size_t)t * 512; lda = LDA_CTX;
        W = Wo1 + 1024; ldw = 1536; K = 512; bias = b_o1;
        C = octx;
    }
    gemm_tile64(A, lda, 256, b0, W, ldw, n0, K, At, Wt, acc);
    int tx = threadIdx.x & 15, ty = threadIdx.x >> 4;
#pragma unroll
    for (int i = 0; i < 4; ++i) {
        int b = b0 + ty * 4 + i;
#pragma unroll
        for (int j = 0; j < 4; ++j) {
            int n = n0 + tx * 4 + j;
            float v = acc[i][j];
            if (bias) v += bias[n];
            C[(size_t)b * 1024 + n] = v;
        }
    }
}

__global__ void kb_kernel(const float* __restrict__ hg, const float* __restrict__ Wo1,
                          const float* __restrict__ uv, const float* __restrict__ octx,
                          const float* __restrict__ mbuf, const float* __restrict__ isbuf,
                          float* __restrict__ o)
{
    __shared__ __align__(16) float At[16 * TS];
    __shared__ __align__(16) float Wt[16 * TS];
    float acc[2][4] = {};
    const int b0 = blockIdx.x * 32, n0 = blockIdx.y * 64;
    const int tid = threadIdx.x, tx = tid & 15, ty = tid >> 4;
    const int r = tid >> 2, c0 = (tid & 3) << 2;
    for (int k0 = 0; k0 < 1024; k0 += 16) {
        float4 av = make_float4(0.f, 0.f, 0.f, 0.f);
        if (r < 32) av = *(const float4*)(hg + (size_t)(b0 + r) * 1024 + k0 + c0);
        float4 wv = *(const float4*)(Wo1 + (size_t)(n0 + r) * 1536 + k0 + c0);
        __syncthreads();
        At[(c0+0)*TS + r] = av.x; At[(c0+1)*TS + r] = av.y;
        At[(c0+2)*TS + r] = av.z; At[(c0+3)*TS + r] = av.w;
        Wt[(c0+0)*TS + r] = wv.x; Wt[(c0+1)*TS + r] = wv.y;
        Wt[(c0+2)*TS + r] = wv.z; Wt[(c0+3)*TS + r] = wv.w;
        __syncthreads();
#pragma unroll
        for (int kk = 0; kk < 16; ++kk) {
            float2 a = *(const float2*)(At + kk*TS + ty*2);
            float4 w = *(const float4*)(Wt + kk*TS + tx*4);
            acc[0][0] += a.x*w.x; acc[0][1] += a.x*w.y; acc[0][2] += a.x*w.z; acc[0][3] += a.x*w.w;
            acc[1][0] += a.y*w.x; acc[1][1] += a.y*w.y; acc[1][2] += a.y*w.z; acc[1][3] += a.y*w.w;
        }
    }
#pragma unroll
    for (int i = 0; i < 2; ++i) {
        int b = b0 + ty * 2 + i;
        float m = mbuf[b], is = isbuf[b];
#pragma unroll
        for (int j = 0; j < 4; ++j) {
            int n = n0 + tx * 4 + j;
            float v = (acc[i][j] - m * uv[n]) * is + uv[1024 + n] + octx[(size_t)b * 1024 + n];
            o[(size_t)b * 1024 + n] = fmaxf(v, 0.f);
        }
    }
}

__global__ void gru_ln_kernel(const float* __restrict__ g6,
                              const float* __restrict__ b_ih, const float* __restrict__ b_hh,
                              float* __restrict__ hBase, const float* __restrict__ ln_g,
                              float* __restrict__ hg, float* __restrict__ mbuf,
                              float* __restrict__ isbuf, int t)
{
    __shared__ float rs[256], rq[256];
    int b = blockIdx.x, tid = threadIdx.x;
    const float* hc = hBase + (size_t)(t & 1) * SZ + (size_t)b * 1024;
    float* hnx = hBase + (size_t)((t + 1) & 1) * SZ + (size_t)b * 1024;
    float s = 0.f, q = 0.f;
#pragma unroll
    for (int jj = 0; jj < 4; ++jj) {
        int j = jj * 256 + tid;
        size_t base = (size_t)b * 1024 + j;
        float xr = g6[0 * (size_t)SZ + base] + b_ih[j];
        float xz = g6[1 * (size_t)SZ + base] + b_ih[1024 + j];
        float xn = g6[2 * (size_t)SZ + base] + b_ih[2048 + j];
        float hr = g6[3 * (size_t)SZ + base] + b_hh[j];
        float hz = g6[4 * (size_t)SZ + base] + b_hh[1024 + j];
        float hn = g6[5 * (size_t)SZ + base] + b_hh[2048 + j];
        float r = 1.f / (1.f + expf(-(xr + hr)));
        float z = 1.f / (1.f + expf(-(xz + hz)));
        float nn = tanhf(xn + r * hn);
        float ho = hc[j];
        float hv = (1.f - z) * nn + z * ho;
        hnx[j] = hv;
        hg[base] = hv * ln_g[j];
        s += hv; q += hv * hv;
    }
    rs[tid] = s; rq[tid] = q;
    __syncthreads();
    for (int st = 128; st; st >>= 1) {
        if (tid < st) { rs[tid] += rs[tid + st]; rq[tid] += rq[tid + st]; }
        __syncthreads();
    }
    if (tid == 0) {
        float m = rs[0] * (1.f / 1024.f);
        float var = rq[0] * (1.f / 1024.f) - m * m;
        mbuf[b] = m;
        isbuf[b] = rsqrtf(var + 1e-5f);
    }
}

__global__ void kc_kernel(const float* __restrict__ o, const float* __restrict__ Wo2t,
                          const float* __restrict__ b_o2, const float* __restrict__ cinBase,
                          const float* __restrict__ bpart, float* __restrict__ x,
                          int* __restrict__ prev, float* __restrict__ out, int t)
{
    __shared__ __align__(16) float os[1024];
    __shared__ float red[4][64];
    __shared__ int sidx;
    int b = blockIdx.x, tid = threadIdx.x;
    const float* orow = o + (size_t)b * 1024;
    *(float4*)&os[tid * 4] = *(const float4*)&orow[tid * 4];
    __syncthreads();
    int n = tid & 63, seg = tid >> 6;
    float p = 0.f;
    int k0 = seg * 256;
#pragma unroll 8
    for (int k = 0; k < 256; ++k) p += os[k0 + k] * Wo2t[(size_t)(k0 + k) * 64 + n];
    red[seg][n] = p;
    __syncthreads();
    if (tid < 64) {
        float lg = red[0][tid] + red[1][tid] + red[2][tid] + red[3][tid] + b_o2[tid];
        out[((size_t)b * TT + t) * 64 + tid] = lg;
        float v = lg; int idx = tid;
        for (int off = 32; off; off >>= 1) {
            float ov = __shfl_xor(v, off);
            int oi = __shfl_xor(idx, off);
            if (ov > v || (ov == v && oi < idx)) { v = ov; idx = oi; }
        }
        if (tid == 0) { prev[b] = idx; sidx = idx; }
    }
    __syncthreads();
    if (t + 1 < TT) {
        int pb = sidx;
        const float* cn = cinBase + (size_t)((t + 1) & 1) * SZ + (size_t)b * 1024;
        const float* bp = bpart + (size_t)pb * 1024;
#pragma unroll
        for (int jj = 0; jj < 4; ++jj) {
            int j = jj * 256 + tid;
            x[(size_t)b * 1024 + j] = fmaxf(cn[j] + bp[j], 0.f);
        }
    }
}

__global__ void copy_gb_kernel(const float* g, const float* bb, float* gb)
{
    int idx = blockIdx.x * 256 + threadIdx.x;
    if (idx < 1024) gb[idx] = g[idx];
    else            gb[idx] = bb[idx - 1024];
}

// ---------------------------------------------------------------------------

extern "C" void kernel_launch(void* const* d_in, const int* in_sizes, int n_in,
                              void* d_out, int out_size, void* d_ws, size_t ws_size,
                              hipStream_t stream)
{
    const float* ctx    = (const float*)d_in[0];
    const int*   bh     = (const int*)d_in[1];
    const float* be     = (const float*)d_in[2];
    const float* W_in   = (const float*)d_in[3];
    const float* b_in   = (const float*)d_in[4];
    const float* W_init = (const float*)d_in[5];
    const float* b_init = (const float*)d_in[6];
    const float* W_ih   = (const float*)d_in[7];
    const float* b_ih   = (const float*)d_in[8];
    const float* W_hh   = (const float*)d_in[9];
    const float* b_hh   = (const float*)d_in[10];
    const float* ln_g   = (const float*)d_in[11];
    const float* ln_b   = (const float*)d_in[12];
    const float* W_o1   = (const float*)d_in[13];
    const float* b_o1   = (const float*)d_in[14];
    const float* W_o2   = (const float*)d_in[15];
    const float* b_o2   = (const float*)d_in[16];
    float* out = (float*)d_out;
    float* ws  = (float*)d_ws;

    const bool mfma_path = (ws_size >= 45700000ull);

    if (mfma_path) {
        // ---- round-13 layout (floats) ----
        float* hbuf  = ws;                  // 256x1024 fp32, in-place h
        float* cin   = ws + 262144;
        float* octx  = ws + 524288;
        float* g6    = ws + 786432;         // 6 slots; 0..3 reused as kb partials
        float* A0    = g6;                  // setup-only alias
        float* bpart = ws + 2359296;        // 64x1024
        float* uvv   = ws + 2424832;        // 2x1024
        float* Wo2t  = ws + 2428928;        // 1024x64
        float* mbuf  = ws + 2494464;
        float* isbuf = ws + 2494720;
        int*   prev  = (int*)(ws + 2494976);
        unsigned short* bf = (unsigned short*)(ws + 2495232);
        unsigned short* wih_hiP  = bf;                  // packed frags
        unsigned short* wih_loP  = bf + 3145728;
        unsigned short* whh_hiP  = bf + 6291456;
        unsigned short* whh_loP  = bf + 9437184;
        unsigned short* wo1k_hiP = bf + 12582912;       // packed, ln_g-folded
        unsigned short* wo1k_loP = bf + 13631488;
        unsigned short* wo1c_hi  = bf + 14680064;       // [1024x512] row-major
        unsigned short* wo1c_lo  = bf + 15204352;
        unsigned short* wcin_hi  = bf + 15728640;       // [1024x512] row-major
        unsigned short* wcin_lo  = bf + 16252928;
        unsigned short* xh       = bf + 16777216;
        unsigned short* xl       = bf + 17039360;
        unsigned short* hh       = bf + 17301504;
        unsigned short* hl       = bf + 17563648;
        // end: 2495232*4 + 17825792*2 = 45,632,512 B

        // ---- setup ----
        pre0_kernel<<<256, 512, 0, stream>>>(ctx, bh, be, A0, prev);
        wo2t_kernel<<<256, 256, 0, stream>>>(W_o2, Wo2t);
        uv_kernel<<<8, 256, 0, stream>>>(ln_g, ln_b, W_o1, uvv);
        gemm64_kernel<<<dim3(4, 16), 256, 0, stream>>>(A0, 1024, 256, W_init, 1024, 1024,
                                                       b_init, hbuf, 1024, 1);
        gemm64_kernel<<<dim3(1, 16), 256, 0, stream>>>(be, 512, 64, W_in + 512, 1024, 512,
                                                       nullptr, bpart, 1024, 0);
        gemm64_kernel<<<dim3(4, 16), 256, 0, stream>>>(ctx, LDA_CTX, 256, W_in, 1024, 512,
                                                       b_in, cin, 1024, 0);
        xbuild0s_kernel<<<256, 256, 0, stream>>>(cin, bpart, prev, xh, xl);
        // weight preprocessing: packed hi + packed lo for gate/kb weights
        packhi_kernel<<<12288, 256, 0, stream>>>(W_ih, 1024, 0, 3072, 1024, nullptr, wih_hiP);
        packlo_kernel<<<12288, 256, 0, stream>>>(W_ih, 1024, 0, 3072, 1024, nullptr, wih_loP);
        packhi_kernel<<<12288, 256, 0, stream>>>(W_hh, 1024, 0, 3072, 1024, nullptr, whh_hiP);
        packlo_kernel<<<12288, 256, 0, stream>>>(W_hh, 1024, 0, 3072, 1024, nullptr, whh_loP);
        packhi_kernel<<<4096, 256, 0, stream>>>(W_o1, 1536, 0, 1024, 1024, ln_g, wo1k_hiP);
        packlo_kernel<<<4096, 256, 0, stream>>>(W_o1, 1536, 0, 1024, 1024, ln_g, wo1k_loP);
        wsplit_kernel<<<2048, 256, 0, stream>>>(W_o1, 1536, 1024, 1024, 512, nullptr, wo1c_hi, wo1c_lo);
        wsplit_kernel<<<2048, 256, 0, stream>>>(W_in, 1024, 0, 1024, 512, nullptr, wcin_hi, wcin_lo);
        // h0 split
        wsplit_kernel<<<1024, 256, 0, stream>>>(hbuf, 1024, 0, 256, 1024, nullptr, hh, hl);

        // ---- recurrence: 4 launches/step ----
        for (int t = 0; t < TT; ++t) {
            gates13_kernel<<<256, 256, 0, stream>>>(
                xh, xl, hh, hl, ctx,
                wih_hiP, wih_loP, whh_hiP, whh_loP, wcin_hi, wcin_lo, wo1c_hi, wo1c_lo,
                b_in, b_o1, g6, cin, octx, t);
            gru13_kernel<<<256, 256, 0, stream>>>(g6, b_ih, b_hh, hbuf,
                                                  hh, hl, mbuf, isbuf);
            kb13_kernel<<<128, 256, 0, stream>>>(hh, hl, wo1k_hiP, wo1k_loP, g6);
            kc13_kernel<<<64, 256, 0, stream>>>(g6, Wo2t, b_o2, uvv, octx, mbuf, isbuf,
                                                cin, bpart, xh, xl, prev, out, t);
        }
    } else {
        // ---- fallback: round-1 fp32 path ----
        float* A0    = ws;
        float* hbuf  = ws + 262144;
        float* hg    = ws + 786432;
        float* x     = ws + 1048576;
        float* cin   = ws + 1310720;
        float* octx  = ws + 1835008;
        float* g6    = ws + 2097152;
        float* obuf  = ws + 3670016;
        float* bpart = ws + 3932160;
        float* uvv   = ws + 3997696;
        float* gb    = ws + 3999744;
        float* Wo2t  = ws + 4001792;
        float* mbuf  = ws + 4067328;
        float* isbuf = ws + 4067584;
        int*   prev  = (int*)(ws + 4067840);

        pre0_kernel<<<256, 512, 0, stream>>>(ctx, bh, be, A0, prev);
        copy_gb_kernel<<<8, 256, 0, stream>>>(ln_g, ln_b, gb);
        wo2t_kernel<<<256, 256, 0, stream>>>(W_o2, Wo2t);
        gemm64_kernel<<<dim3(4, 16), 256, 0, stream>>>(A0, 1024, 256, W_init, 1024, 1024,
                                                       b_init, hbuf, 1024, 1);
        gemm64_kernel<<<dim3(1, 16), 256, 0, stream>>>(be, 512, 64, W_in + 512, 1024, 512,
                                                       nullptr, bpart, 1024, 0);
        gemm64_kernel<<<dim3(1, 16), 256, 0, stream>>>(gb, 1024, 2, W_o1, 1536, 1024,
                                                       nullptr, uvv, 1024, 0);
        gemm64_kernel<<<dim3(4, 16), 256, 0, stream>>>(ctx, LDA_CTX, 256, W_in, 1024, 512,
                                                       b_in, cin, 1024, 0);
        xbuild0_kernel<<<256, 256, 0, stream>>>(cin, bpart, prev, x);

        for (int t = 0; t < TT; ++t) {
            step_gemms_kernel<<<dim3(4, 16, 8), 256, 0, stream>>>(
                x, hbuf, ctx, W_ih, W_hh, W_in, W_o1, b_in, b_o1, g6, cin, octx, t);
            gru_ln_kernel<<<256, 256, 0, stream>>>(g6, b_ih, b_hh, hbuf, ln_g, hg,
                                                   mbuf, isbuf, t);
            kb_kernel<<<dim3(8, 16), 256, 0, stream>>>(hg, W_o1, uvv, octx, mbuf, isbuf, obuf);
            kc_kernel<<<256, 256, 0, stream>>>(obuf, Wo2t, b_o2, cin, bpart, x, prev, out, t);
        }
    }
}